// Round 4
// baseline (1700.902 us; speedup 1.0000x reference)
//
#include <hip/hip_runtime.h>

typedef __attribute__((ext_vector_type(4))) float f32x4;
typedef __attribute__((ext_vector_type(8))) short s16x8;

#define MTOTW 65792   // 257*256: fp32 W stride per a-index

__device__ __forceinline__ short f2bf(float f) {
    unsigned u = __builtin_bit_cast(unsigned, f);
    u = (u + 0x7fffu + ((u >> 16) & 1u)) >> 16;   // RNE
    return (short)u;
}

// async global->LDS, 16B per lane: LDS dest = uniform base + lane*16 (m97/m104)
__device__ __forceinline__ void gl16(const void* g, void* l) {
    __builtin_amdgcn_global_load_lds(
        (const __attribute__((address_space(1))) unsigned int*)g,
        (__attribute__((address_space(3))) unsigned int*)l, 16, 0, 0);
}

// ---------- prep: l1,l2 -> bf16 (flat) ----------
__global__ __launch_bounds__(256) void conv_bf16(
    const float* __restrict__ a, const float* __restrict__ b,
    short* __restrict__ ao, short* __restrict__ bo)
{
    int i = blockIdx.x * 256 + threadIdx.x;
    const int HALF = 131072;
    float4 v; short* dst;
    if (i < HALF) { v = ((const float4*)a)[i]; dst = ao + (size_t)i * 4; }
    else          { v = ((const float4*)b)[i - HALF]; dst = bo + (size_t)(i - HALF) * 4; }
    short4 o; o.x = f2bf(v.x); o.y = f2bf(v.y); o.z = f2bf(v.z); o.w = f2bf(v.w);
    *(short4*)dst = o;
}

// ---------- prep: W3t[d][c] = bf16(W3[c][d]) ----------
__global__ __launch_bounds__(256) void prep_w3t(
    const float* __restrict__ W3, short* __restrict__ W3t)
{
    __shared__ float ld[32][33];
    int t = threadIdx.x, bx = blockIdx.x;
    int c0 = (bx >> 3) * 32, d0 = (bx & 7) * 32;
    int cr = t >> 3, dq = t & 7;
    float4 v = *(const float4*)&W3[(size_t)(c0 + cr) * 256 + d0 + dq * 4];
    ld[cr][dq*4+0] = v.x; ld[cr][dq*4+1] = v.y; ld[cr][dq*4+2] = v.z; ld[cr][dq*4+3] = v.w;
    __syncthreads();
    int dr = t >> 3, cq = t & 7;
    short4 o;
    o.x = f2bf(ld[cq*4+0][dr]); o.y = f2bf(ld[cq*4+1][dr]);
    o.z = f2bf(ld[cq*4+2][dr]); o.w = f2bf(ld[cq*4+3][dr]);
    *(short4*)&W3t[(size_t)(d0 + dr) * 256 + c0 + cq * 4] = o;
}

// ---------- prep: Wtp[c][a] = bf16(W[a][256][c]) (the b=256 plane, transposed) ----------
__global__ __launch_bounds__(256) void prep_wtail(
    const float* __restrict__ W1, const float* __restrict__ W2,
    short* __restrict__ Wtp1, short* __restrict__ Wtp2)
{
    __shared__ float ld[32][33];
    int t = threadIdx.x, bx = blockIdx.x;
    const float* W = blockIdx.y ? W2 : W1;
    short* Wtp = blockIdx.y ? Wtp2 : Wtp1;
    int a0 = (bx >> 3) * 32, c0 = (bx & 7) * 32;
    int ar = t >> 3, cq = t & 7;
    float4 v = *(const float4*)&W[(size_t)(a0 + ar) * MTOTW + 65536 + c0 + cq * 4];
    ld[ar][cq*4+0] = v.x; ld[ar][cq*4+1] = v.y; ld[ar][cq*4+2] = v.z; ld[ar][cq*4+3] = v.w;
    __syncthreads();
    int cr = t >> 3, aq = t & 7;
    short4 o;
    o.x = f2bf(ld[aq*4+0][cr]); o.y = f2bf(ld[aq*4+1][cr]);
    o.z = f2bf(ld[aq*4+2][cr]); o.w = f2bf(ld[aq*4+3][cr]);
    *(short4*)&Wtp[(size_t)(c0 + cr) * 256 + a0 + aq * 4] = o;
}

// ---------- prep: Wp[c][b][a] = bf16(W[a][b][c]) ----------
__global__ __launch_bounds__(256) void prep_wp(
    const float* __restrict__ W1, const float* __restrict__ W2,
    short* __restrict__ Wp1, short* __restrict__ Wp2)
{
    __shared__ float ld[32][33];
    int t = threadIdx.x, bx = blockIdx.x;
    int b = blockIdx.y;
    const float* W = blockIdx.z ? W2 : W1;
    short* Wp = blockIdx.z ? Wp2 : Wp1;
    int a0 = (bx >> 3) * 32, c0 = (bx & 7) * 32;
    int ar = t >> 3, cq = t & 7;
    float4 v = *(const float4*)&W[(size_t)(a0 + ar) * MTOTW + (size_t)b * 256 + c0 + cq * 4];
    ld[ar][cq*4+0] = v.x; ld[ar][cq*4+1] = v.y; ld[ar][cq*4+2] = v.z; ld[ar][cq*4+3] = v.w;
    __syncthreads();
    int cr = t >> 3, aq = t & 7;
    short4 o;
    o.x = f2bf(ld[aq*4+0][cr]); o.y = f2bf(ld[aq*4+1][cr]);
    o.z = f2bf(ld[aq*4+2][cr]); o.w = f2bf(ld[aq*4+3][cr]);
    *(short4*)&Wp[((size_t)(c0 + cr) * 256 + b) * 256 + a0 + aq * 4] = o;
}

// ---------- tail_mfma: tail[r][c] = sum_{a<256} l1b[r][a]*Wtp[c][a] + W[256][256][c] ----------
// grid (16 rt, 2 nt, 2 ten), block 256; M=128 N=128 K=256
__global__ __launch_bounds__(256, 2) void tail_mfma(
    const short* __restrict__ l1b,
    const short* __restrict__ Wtp1, const short* __restrict__ Wtp2,
    const float* __restrict__ W1, const float* __restrict__ W2,
    float* __restrict__ tail1, float* __restrict__ tail2)
{
    __shared__ __align__(16) short Al[128 * 32];
    __shared__ __align__(16) short Bl[128 * 32];
    int t = threadIdx.x, w = t >> 6, lane = t & 63;
    int l4 = lane >> 2, kq = lane & 3;
    int rt = blockIdx.x, nt = blockIdx.y, ten = blockIdx.z;
    const short* Wtp = ten ? Wtp2 : Wtp1;
    const float* Wf = ten ? W2 : W1;
    float* tail = ten ? tail2 : tail1;
    const short* Ab = l1b + (size_t)(rt * 128) * 256;
    const short* Bb = Wtp + (size_t)(nt * 128) * 256;

    f32x4 acc[4][4] = {};
    int m0w = (w >> 1) * 64, n0w = (w & 1) * 64;

    for (int k0 = 0; k0 < 256; k0 += 32) {
        __syncthreads();
        #pragma unroll
        for (int q = 0; q < 4; ++q) {
            int seg = w * 4 + q;
            if (seg < 8)
                gl16(Ab + (size_t)(seg * 16 + l4) * 256 + k0 + kq * 8, &Al[seg * 512]);
            else
                gl16(Bb + (size_t)((seg - 8) * 16 + l4) * 256 + k0 + kq * 8, &Bl[(seg - 8) * 512]);
        }
        __syncthreads();
        s16x8 af[4], bf[4];
        #pragma unroll
        for (int i = 0; i < 4; ++i) {
            af[i] = *(const s16x8*)&Al[(m0w + i * 16 + (lane & 15)) * 32 + (lane >> 4) * 8];
            bf[i] = *(const s16x8*)&Bl[(n0w + i * 16 + (lane & 15)) * 32 + (lane >> 4) * 8];
        }
        #pragma unroll
        for (int mi = 0; mi < 4; ++mi)
            #pragma unroll
            for (int ni = 0; ni < 4; ++ni)
                acc[mi][ni] = __builtin_amdgcn_mfma_f32_16x16x32_bf16(af[mi], bf[ni], acc[mi][ni], 0, 0, 0);
    }
    #pragma unroll
    for (int ni = 0; ni < 4; ++ni) {
        int c = nt * 128 + n0w + ni * 16 + (lane & 15);
        float tl = Wf[(size_t)256 * MTOTW + 65536 + c];   // a=256,b=256 term (coeff 1)
        #pragma unroll
        for (int mi = 0; mi < 4; ++mi) {
            int r = rt * 128 + m0w + mi * 16 + (lane >> 4) * 4;
            #pragma unroll
            for (int reg = 0; reg < 4; ++reg)
                tail[(size_t)(r + reg) * 256 + c] = acc[mi][ni][reg] + tl;
        }
    }
}

// ---------- stage1: T[rl][c][b] = bf16( sum_a l1b[r][a]*Wp[c][b][a] + W[256][b][c] ) ----------
// R1 schedule (gl16 staging, 2 barriers/K-step) + LDS union: staging 16 KB
// overlaid by the 32 KB epilogue repack -> 32 KB total -> 4-5 blocks/CU.
__global__ __launch_bounds__(256, 4) void stage1(
    const short* __restrict__ l1b,
    const short* __restrict__ Wp1, const short* __restrict__ Wp2,
    const float* __restrict__ W1, const float* __restrict__ W2,
    short* __restrict__ T1, short* __restrict__ T2, int row0)
{
    __shared__ __align__(16) short S[16384];   // union: {Al[0,4096)|Bl[4096,8192)} / Cep[0,16384)
    int t = threadIdx.x, w = t >> 6, lane = t & 63;
    int l4 = lane >> 2, kq = lane & 3;

    // --- bijective XCD-aware swizzle (nwg % 8 == 0 always: gdx*2*512) ---
    unsigned gdx = gridDim.x;                        // power of 2 (chunk/128)
    unsigned orig = blockIdx.x + gdx * (blockIdx.y + 2u * blockIdx.z);
    unsigned nwg = gdx * 1024u;
    unsigned swz = (orig & 7u) * (nwg >> 3) + (orig >> 3);
    int rt = swz & (gdx - 1u);
    unsigned rest = swz / gdx;
    int bt = rest & 1, zc = rest >> 1;

    int c = zc >> 1, ten = zc & 1;
    const short* Wp = ten ? Wp2 : Wp1;
    const float* Wf = ten ? W2 : W1;
    short* T = ten ? T2 : T1;
    int r0g = row0 + rt * 128;
    int b0 = bt * 128;
    const short* Ab = l1b + (size_t)r0g * 256;
    const short* Bb = Wp + ((size_t)c * 256 + b0) * 256;

    f32x4 acc[4][4] = {};
    int m0w = (w >> 1) * 64, n0w = (w & 1) * 64;

    for (int k0 = 0; k0 < 256; k0 += 32) {
        __syncthreads();
        #pragma unroll
        for (int q = 0; q < 4; ++q) {
            int seg = w * 4 + q;
            if (seg < 8)
                gl16(Ab + (size_t)(seg * 16 + l4) * 256 + k0 + kq * 8, &S[seg * 512]);
            else
                gl16(Bb + (size_t)((seg - 8) * 16 + l4) * 256 + k0 + kq * 8, &S[4096 + (seg - 8) * 512]);
        }
        __syncthreads();
        s16x8 af[4], bf[4];
        #pragma unroll
        for (int i = 0; i < 4; ++i) {
            af[i] = *(const s16x8*)&S[(m0w + i * 16 + (lane & 15)) * 32 + (lane >> 4) * 8];
            bf[i] = *(const s16x8*)&S[4096 + (n0w + i * 16 + (lane & 15)) * 32 + (lane >> 4) * 8];
        }
        #pragma unroll
        for (int mi = 0; mi < 4; ++mi)
            #pragma unroll
            for (int ni = 0; ni < 4; ++ni)
                acc[mi][ni] = __builtin_amdgcn_mfma_f32_16x16x32_bf16(af[mi], bf[ni], acc[mi][ni], 0, 0, 0);
    }
    __syncthreads();   // all waves done reading staging before Cep overlays it

    // epilogue: repack wave's 64x64 through LDS (per-wave region, no further sync)
    short* Cw = &S[w * 4096];
    #pragma unroll
    for (int ni = 0; ni < 4; ++ni) {
        int b = b0 + n0w + ni * 16 + (lane & 15);
        float tl = Wf[(size_t)256 * MTOTW + (size_t)b * 256 + c];   // a=256 tail, fp32
        #pragma unroll
        for (int mi = 0; mi < 4; ++mi)
            #pragma unroll
            for (int reg = 0; reg < 4; ++reg) {
                int lr = mi * 16 + (lane >> 4) * 4 + reg;           // wave-local row
                int lc = ni * 16 + (lane & 15);                     // wave-local col
                Cw[lr * 64 + lc] = f2bf(acc[mi][ni][reg] + tl);
            }
    }
    #pragma unroll
    for (int s = 0; s < 8; ++s) {
        int row = s * 8 + (lane >> 3);
        int co = (lane & 7) * 8;
        int rl = rt * 128 + m0w + row;                              // chunk-local row
        int gb = b0 + n0w + co;
        *(int4*)&T[((size_t)rl * 256 + c) * 256 + gb] = *(int4*)&Cw[row * 64 + co];
    }
}

// ---------- stage2: merged U1/U2 (shared A), then V1(LDS)->P->dot ----------
// R1 schedule + LDS union (52 KB -> 3 blocks/CU):
//   phase A: Al[0,2048) | B1l[2048,10240) | B2l[10240,18432)  (shorts)
//   then:    V1[0,16896) | part[16896,17408) | W3t-staging[18432,26624)
// XCD-swizzled so jt-siblings' T re-reads stay L2-local.
__global__ __launch_bounds__(256, 3) void stage2(
    const short* __restrict__ l2b,
    const short* __restrict__ T1, const short* __restrict__ T2,
    const float* __restrict__ tail1, const float* __restrict__ tail2,
    const float* __restrict__ h1, const float* __restrict__ h2,
    const short* __restrict__ W3t, float* __restrict__ out, int row0)
{
    __shared__ __align__(16) short S2[26624];   // 52 KB
    int t = threadIdx.x, w = t >> 6, lane = t & 63;
    int l4 = lane >> 2, kq = lane & 3;

    // --- bijective XCD-aware swizzle (nwg = 4*chunk, chunk pow2 -> %8==0) ---
    unsigned orig = blockIdx.x + (blockIdx.y << 2);
    unsigned nwg = gridDim.y << 2;
    unsigned swz = (orig & 7u) * (nwg >> 3) + (orig >> 3);
    int jt = swz & 3, rl = swz >> 2;

    int rg = row0 + rl, n = rg >> 8, j0 = jt * 64;
    const short* Arow = l2b + ((size_t)n * 256 + j0) * 256;
    const short* Tt1 = T1 + (size_t)rl * 65536;
    const short* Tt2 = T2 + (size_t)rl * 65536;
    int n0w = w * 64;

    // ---- phase A: U1 and U2 together (A shared) ----
    f32x4 acc1[4][4] = {}, acc2[4][4] = {};
    for (int k0 = 0; k0 < 256; k0 += 32) {
        __syncthreads();
        #pragma unroll
        for (int q = 0; q < 9; ++q) {              // 4 Al + 16 B1 + 16 B2 = 36 segs
            int seg = w * 9 + q;
            const short* gb; short* lb;
            if (seg < 4)       { gb = Arow + (size_t)(seg * 16 + l4) * 256;        lb = &S2[seg * 512]; }
            else if (seg < 20) { int s = seg - 4;  gb = Tt1 + (size_t)(s * 16 + l4) * 256; lb = &S2[2048 + s * 512]; }
            else               { int s = seg - 20; gb = Tt2 + (size_t)(s * 16 + l4) * 256; lb = &S2[10240 + s * 512]; }
            gl16(gb + k0 + kq * 8, lb);
        }
        __syncthreads();
        s16x8 af[4], b1[4], b2[4];
        #pragma unroll
        for (int i = 0; i < 4; ++i) {
            af[i] = *(const s16x8*)&S2[(i * 16 + (lane & 15)) * 32 + (lane >> 4) * 8];
            b1[i] = *(const s16x8*)&S2[2048 + (n0w + i * 16 + (lane & 15)) * 32 + (lane >> 4) * 8];
            b2[i] = *(const s16x8*)&S2[10240 + (n0w + i * 16 + (lane & 15)) * 32 + (lane >> 4) * 8];
        }
        #pragma unroll
        for (int mi = 0; mi < 4; ++mi)
            #pragma unroll
            for (int ni = 0; ni < 4; ++ni) {
                acc1[mi][ni] = __builtin_amdgcn_mfma_f32_16x16x32_bf16(af[mi], b1[ni], acc1[mi][ni], 0, 0, 0);
                acc2[mi][ni] = __builtin_amdgcn_mfma_f32_16x16x32_bf16(af[mi], b2[ni], acc2[mi][ni], 0, 0, 0);
            }
    }
    __syncthreads();   // all waves done reading phase-A staging before V1 overlays it

    // V1 = h1*(U1+tail1) -> LDS bf16 ; v2 = h2*(U2+tail2) -> regs
    short* V1 = S2;                                  // [64][264], overlays phase-A bufs
    f32x4 v2[4][4];
    #pragma unroll
    for (int ni = 0; ni < 4; ++ni) {
        int c = n0w + ni * 16 + (lane & 15);
        float hh1 = h1[(size_t)rg * 256 + c], tl1 = tail1[(size_t)rg * 256 + c];
        float hh2 = h2[(size_t)rg * 256 + c], tl2 = tail2[(size_t)rg * 256 + c];
        #pragma unroll
        for (int mi = 0; mi < 4; ++mi)
            #pragma unroll
            for (int reg = 0; reg < 4; ++reg) {
                int j = mi * 16 + (lane >> 4) * 4 + reg;
                V1[j * 264 + c] = f2bf(hh1 * (acc1[mi][ni][reg] + tl1));
                v2[mi][ni][reg] = hh2 * (acc2[mi][ni][reg] + tl2);
            }
    }
    __syncthreads();   // V1 visible to all waves

    // ---- phase B: P = V1 @ W3t^T (A from V1-LDS, B=W3t staged at S2[18432..26624)) ----
    f32x4 accP[4][4] = {};
    for (int k0 = 0; k0 < 256; k0 += 32) {
        __syncthreads();
        #pragma unroll
        for (int q = 0; q < 4; ++q) {
            int s = w * 4 + q;
            gl16(W3t + (size_t)(s * 16 + l4) * 256 + k0 + kq * 8, &S2[18432 + s * 512]);
        }
        __syncthreads();
        s16x8 af[4], bf[4];
        #pragma unroll
        for (int i = 0; i < 4; ++i) {
            af[i] = *(const s16x8*)&V1[(i * 16 + (lane & 15)) * 264 + k0 + (lane >> 4) * 8];
            bf[i] = *(const s16x8*)&S2[18432 + (n0w + i * 16 + (lane & 15)) * 32 + (lane >> 4) * 8];
        }
        #pragma unroll
        for (int mi = 0; mi < 4; ++mi)
            #pragma unroll
            for (int ni = 0; ni < 4; ++ni)
                accP[mi][ni] = __builtin_amdgcn_mfma_f32_16x16x32_bf16(af[mi], bf[ni], accP[mi][ni], 0, 0, 0);
    }

    // out[j] = sum_d P[j][d] * V2[j][d]
    float* part = (float*)&S2[16896];                // disjoint from V1 and W3t staging
    #pragma unroll
    for (int mi = 0; mi < 4; ++mi)
        #pragma unroll
        for (int reg = 0; reg < 4; ++reg) {
            float s = 0.f;
            #pragma unroll
            for (int ni = 0; ni < 4; ++ni) s += accP[mi][ni][reg] * v2[mi][ni][reg];
            s += __shfl_xor(s, 1); s += __shfl_xor(s, 2);
            s += __shfl_xor(s, 4); s += __shfl_xor(s, 8);
            if ((lane & 15) == 0)
                part[(mi * 16 + (lane >> 4) * 4 + reg) * 4 + w] = s;
        }
    __syncthreads();
    if (t < 64)
        out[(size_t)rg * 256 + j0 + t] = part[t*4] + part[t*4+1] + part[t*4+2] + part[t*4+3];
}

extern "C" void kernel_launch(void* const* d_in, const int* in_sizes, int n_in,
                              void* d_out, int out_size, void* d_ws, size_t ws_size,
                              hipStream_t stream) {
    const float* layer1 = (const float*)d_in[0];
    const float* layer2 = (const float*)d_in[1];
    const float* h1     = (const float*)d_in[2];
    const float* h2     = (const float*)d_in[3];
    const float* W1     = (const float*)d_in[4];
    const float* W2     = (const float*)d_in[5];
    const float* W3     = (const float*)d_in[6];
    float* out = (float*)d_out;

    short* Wp1  = (short*)d_ws;                  // 33.55 MB
    short* Wp2  = Wp1 + 16777216;
    short* l1b  = Wp2 + 16777216;                // 2048x256
    short* l2b  = l1b + 524288;
    short* W3t  = l2b + 524288;                  // 256x256
    short* Wtp1 = W3t + 65536;                   // 256x256
    short* Wtp2 = Wtp1 + 65536;
    float* tail1 = (float*)(Wtp2 + 65536);       // 2048x256 fp32
    float* tail2 = tail1 + 524288;
    short* T1   = (short*)(tail2 + 524288);
    const size_t head = (size_t)(16777216*2 + 524288*2 + 65536*3) * 2 + (size_t)524288 * 2 * 4;
    int chunk = 2048;
    while (head + (size_t)chunk * 262144 > ws_size && chunk > 128) chunk >>= 1;
    short* T2 = T1 + (size_t)chunk * 65536;

    conv_bf16<<<1024, 256, 0, stream>>>(layer1, layer2, l1b, l2b);
    prep_w3t<<<64, 256, 0, stream>>>(W3, W3t);
    prep_wtail<<<dim3(64, 2), 256, 0, stream>>>(W1, W2, Wtp1, Wtp2);
    prep_wp<<<dim3(64, 256, 2), 256, 0, stream>>>(W1, W2, Wp1, Wp2);
    tail_mfma<<<dim3(16, 2, 2), 256, 0, stream>>>(l1b, Wtp1, Wtp2, W1, W2, tail1, tail2);

    for (int row0 = 0; row0 < 2048; row0 += chunk) {
        stage1<<<dim3(chunk / 128, 2, 512), 256, 0, stream>>>(
            l1b, Wp1, Wp2, W1, W2, T1, T2, row0);
        stage2<<<dim3(4, chunk), 256, 0, stream>>>(
            l2b, T1, T2, tail1, tail2, h1, h2, W3t, out, row0);
    }
}

// Round 5
// 773.418 us; speedup vs baseline: 2.1992x; 2.1992x over previous
//
#include <hip/hip_runtime.h>

typedef __attribute__((ext_vector_type(4))) float f32x4;
typedef __attribute__((ext_vector_type(8))) short s16x8;

#define MTOTW 65792   // 257*256: fp32 W stride per a-index

__device__ __forceinline__ short f2bf(float f) {
    unsigned u = __builtin_bit_cast(unsigned, f);
    u = (u + 0x7fffu + ((u >> 16) & 1u)) >> 16;   // RNE
    return (short)u;
}

// async global->LDS, 16B per lane: LDS dest = uniform base + lane*16 (m97/m104)
__device__ __forceinline__ void gl16(const void* g, void* l) {
    __builtin_amdgcn_global_load_lds(
        (const __attribute__((address_space(1))) unsigned int*)g,
        (__attribute__((address_space(3))) unsigned int*)l, 16, 0, 0);
}

// ---------- prep: l1,l2 -> bf16 (flat) ----------
__global__ __launch_bounds__(256) void conv_bf16(
    const float* __restrict__ a, const float* __restrict__ b,
    short* __restrict__ ao, short* __restrict__ bo)
{
    int i = blockIdx.x * 256 + threadIdx.x;
    const int HALF = 131072;
    float4 v; short* dst;
    if (i < HALF) { v = ((const float4*)a)[i]; dst = ao + (size_t)i * 4; }
    else          { v = ((const float4*)b)[i - HALF]; dst = bo + (size_t)(i - HALF) * 4; }
    short4 o; o.x = f2bf(v.x); o.y = f2bf(v.y); o.z = f2bf(v.z); o.w = f2bf(v.w);
    *(short4*)dst = o;
}

// ---------- prep: W3t[d][c] = bf16(W3[c][d]) ----------
__global__ __launch_bounds__(256) void prep_w3t(
    const float* __restrict__ W3, short* __restrict__ W3t)
{
    __shared__ float ld[32][33];
    int t = threadIdx.x, bx = blockIdx.x;
    int c0 = (bx >> 3) * 32, d0 = (bx & 7) * 32;
    int cr = t >> 3, dq = t & 7;
    float4 v = *(const float4*)&W3[(size_t)(c0 + cr) * 256 + d0 + dq * 4];
    ld[cr][dq*4+0] = v.x; ld[cr][dq*4+1] = v.y; ld[cr][dq*4+2] = v.z; ld[cr][dq*4+3] = v.w;
    __syncthreads();
    int dr = t >> 3, cq = t & 7;
    short4 o;
    o.x = f2bf(ld[cq*4+0][dr]); o.y = f2bf(ld[cq*4+1][dr]);
    o.z = f2bf(ld[cq*4+2][dr]); o.w = f2bf(ld[cq*4+3][dr]);
    *(short4*)&W3t[(size_t)(d0 + dr) * 256 + c0 + cq * 4] = o;
}

// ---------- prep: Wtp[c][a] = bf16(W[a][256][c]) (the b=256 plane, transposed) ----------
__global__ __launch_bounds__(256) void prep_wtail(
    const float* __restrict__ W1, const float* __restrict__ W2,
    short* __restrict__ Wtp1, short* __restrict__ Wtp2)
{
    __shared__ float ld[32][33];
    int t = threadIdx.x, bx = blockIdx.x;
    const float* W = blockIdx.y ? W2 : W1;
    short* Wtp = blockIdx.y ? Wtp2 : Wtp1;
    int a0 = (bx >> 3) * 32, c0 = (bx & 7) * 32;
    int ar = t >> 3, cq = t & 7;
    float4 v = *(const float4*)&W[(size_t)(a0 + ar) * MTOTW + 65536 + c0 + cq * 4];
    ld[ar][cq*4+0] = v.x; ld[ar][cq*4+1] = v.y; ld[ar][cq*4+2] = v.z; ld[ar][cq*4+3] = v.w;
    __syncthreads();
    int cr = t >> 3, aq = t & 7;
    short4 o;
    o.x = f2bf(ld[aq*4+0][cr]); o.y = f2bf(ld[aq*4+1][cr]);
    o.z = f2bf(ld[aq*4+2][cr]); o.w = f2bf(ld[aq*4+3][cr]);
    *(short4*)&Wtp[(size_t)(c0 + cr) * 256 + a0 + aq * 4] = o;
}

// ---------- prep: Wp[c][b][a] = bf16(W[a][b][c]) ----------
__global__ __launch_bounds__(256) void prep_wp(
    const float* __restrict__ W1, const float* __restrict__ W2,
    short* __restrict__ Wp1, short* __restrict__ Wp2)
{
    __shared__ float ld[32][33];
    int t = threadIdx.x, bx = blockIdx.x;
    int b = blockIdx.y;
    const float* W = blockIdx.z ? W2 : W1;
    short* Wp = blockIdx.z ? Wp2 : Wp1;
    int a0 = (bx >> 3) * 32, c0 = (bx & 7) * 32;
    int ar = t >> 3, cq = t & 7;
    float4 v = *(const float4*)&W[(size_t)(a0 + ar) * MTOTW + (size_t)b * 256 + c0 + cq * 4];
    ld[ar][cq*4+0] = v.x; ld[ar][cq*4+1] = v.y; ld[ar][cq*4+2] = v.z; ld[ar][cq*4+3] = v.w;
    __syncthreads();
    int cr = t >> 3, aq = t & 7;
    short4 o;
    o.x = f2bf(ld[aq*4+0][cr]); o.y = f2bf(ld[aq*4+1][cr]);
    o.z = f2bf(ld[aq*4+2][cr]); o.w = f2bf(ld[aq*4+3][cr]);
    *(short4*)&Wp[((size_t)(c0 + cr) * 256 + b) * 256 + a0 + aq * 4] = o;
}

// ---------- tail_mfma: tail[r][c] = sum_{a<256} l1b[r][a]*Wtp[c][a] + W[256][256][c] ----------
__global__ __launch_bounds__(256, 2) void tail_mfma(
    const short* __restrict__ l1b,
    const short* __restrict__ Wtp1, const short* __restrict__ Wtp2,
    const float* __restrict__ W1, const float* __restrict__ W2,
    float* __restrict__ tail1, float* __restrict__ tail2)
{
    __shared__ __align__(16) short Al[128 * 32];
    __shared__ __align__(16) short Bl[128 * 32];
    int t = threadIdx.x, w = t >> 6, lane = t & 63;
    int l4 = lane >> 2, kq = lane & 3;
    int rt = blockIdx.x, nt = blockIdx.y, ten = blockIdx.z;
    const short* Wtp = ten ? Wtp2 : Wtp1;
    const float* Wf = ten ? W2 : W1;
    float* tail = ten ? tail2 : tail1;
    const short* Ab = l1b + (size_t)(rt * 128) * 256;
    const short* Bb = Wtp + (size_t)(nt * 128) * 256;

    f32x4 acc[4][4] = {};
    int m0w = (w >> 1) * 64, n0w = (w & 1) * 64;

    for (int k0 = 0; k0 < 256; k0 += 32) {
        __syncthreads();
        #pragma unroll
        for (int q = 0; q < 4; ++q) {
            int seg = w * 4 + q;
            if (seg < 8)
                gl16(Ab + (size_t)(seg * 16 + l4) * 256 + k0 + kq * 8, &Al[seg * 512]);
            else
                gl16(Bb + (size_t)((seg - 8) * 16 + l4) * 256 + k0 + kq * 8, &Bl[(seg - 8) * 512]);
        }
        __syncthreads();
        s16x8 af[4], bf[4];
        #pragma unroll
        for (int i = 0; i < 4; ++i) {
            af[i] = *(const s16x8*)&Al[(m0w + i * 16 + (lane & 15)) * 32 + (lane >> 4) * 8];
            bf[i] = *(const s16x8*)&Bl[(n0w + i * 16 + (lane & 15)) * 32 + (lane >> 4) * 8];
        }
        #pragma unroll
        for (int mi = 0; mi < 4; ++mi)
            #pragma unroll
            for (int ni = 0; ni < 4; ++ni)
                acc[mi][ni] = __builtin_amdgcn_mfma_f32_16x16x32_bf16(af[mi], bf[ni], acc[mi][ni], 0, 0, 0);
    }
    #pragma unroll
    for (int ni = 0; ni < 4; ++ni) {
        int c = nt * 128 + n0w + ni * 16 + (lane & 15);
        float tl = Wf[(size_t)256 * MTOTW + 65536 + c];   // a=256,b=256 term (coeff 1)
        #pragma unroll
        for (int mi = 0; mi < 4; ++mi) {
            int r = rt * 128 + m0w + mi * 16 + (lane >> 4) * 4;
            #pragma unroll
            for (int reg = 0; reg < 4; ++reg)
                tail[(size_t)(r + reg) * 256 + c] = acc[mi][ni][reg] + tl;
        }
    }
}

// ---------- stage1: T[rl][c][b] = bf16( sum_a l1b[r][a]*Wp[c][b][a] + W[256][b][c] ) ----------
// R1 schedule (serial 2-barrier K-steps, gl16 staging) + LDS union:
// 16 KB staging overlaid by 32 KB epilogue repack -> 32 KB total.
// launch_bounds(256,3): cap ~170 VGPR >> demand (~116) -> no spill; LDS allows
// 5 blocks/CU, VGPR allows 4 -> occupancy up from 3 blocks (R1's 48 KB).
__global__ __launch_bounds__(256, 3) void stage1(
    const short* __restrict__ l1b,
    const short* __restrict__ Wp1, const short* __restrict__ Wp2,
    const float* __restrict__ W1, const float* __restrict__ W2,
    short* __restrict__ T1, short* __restrict__ T2, int row0)
{
    __shared__ __align__(16) short S[16384];   // union: {Al[0,4096)|Bl[4096,8192)} / Cep[0,16384)
    int t = threadIdx.x, w = t >> 6, lane = t & 63;
    int l4 = lane >> 2, kq = lane & 3;

    // --- bijective XCD-aware swizzle (nwg % 8 == 0 always: gdx*2*512) ---
    unsigned gdx = gridDim.x;                        // power of 2 (chunk/128)
    unsigned orig = blockIdx.x + gdx * (blockIdx.y + 2u * blockIdx.z);
    unsigned nwg = gdx * 1024u;
    unsigned swz = (orig & 7u) * (nwg >> 3) + (orig >> 3);
    int rt = swz & (gdx - 1u);
    unsigned rest = swz / gdx;
    int bt = rest & 1, zc = rest >> 1;

    int c = zc >> 1, ten = zc & 1;
    const short* Wp = ten ? Wp2 : Wp1;
    const float* Wf = ten ? W2 : W1;
    short* T = ten ? T2 : T1;
    int r0g = row0 + rt * 128;
    int b0 = bt * 128;
    const short* Ab = l1b + (size_t)r0g * 256;
    const short* Bb = Wp + ((size_t)c * 256 + b0) * 256;

    f32x4 acc[4][4] = {};
    int m0w = (w >> 1) * 64, n0w = (w & 1) * 64;

    for (int k0 = 0; k0 < 256; k0 += 32) {
        __syncthreads();
        #pragma unroll
        for (int q = 0; q < 4; ++q) {
            int seg = w * 4 + q;
            if (seg < 8)
                gl16(Ab + (size_t)(seg * 16 + l4) * 256 + k0 + kq * 8, &S[seg * 512]);
            else
                gl16(Bb + (size_t)((seg - 8) * 16 + l4) * 256 + k0 + kq * 8, &S[4096 + (seg - 8) * 512]);
        }
        __syncthreads();
        s16x8 af[4], bf[4];
        #pragma unroll
        for (int i = 0; i < 4; ++i) {
            af[i] = *(const s16x8*)&S[(m0w + i * 16 + (lane & 15)) * 32 + (lane >> 4) * 8];
            bf[i] = *(const s16x8*)&S[4096 + (n0w + i * 16 + (lane & 15)) * 32 + (lane >> 4) * 8];
        }
        #pragma unroll
        for (int mi = 0; mi < 4; ++mi)
            #pragma unroll
            for (int ni = 0; ni < 4; ++ni)
                acc[mi][ni] = __builtin_amdgcn_mfma_f32_16x16x32_bf16(af[mi], bf[ni], acc[mi][ni], 0, 0, 0);
    }
    __syncthreads();   // all waves done reading staging before Cep overlays it

    // epilogue: repack wave's 64x64 through LDS (per-wave region, no further sync)
    short* Cw = &S[w * 4096];
    #pragma unroll
    for (int ni = 0; ni < 4; ++ni) {
        int b = b0 + n0w + ni * 16 + (lane & 15);
        float tl = Wf[(size_t)256 * MTOTW + (size_t)b * 256 + c];   // a=256 tail, fp32
        #pragma unroll
        for (int mi = 0; mi < 4; ++mi)
            #pragma unroll
            for (int reg = 0; reg < 4; ++reg) {
                int lr = mi * 16 + (lane >> 4) * 4 + reg;           // wave-local row
                int lc = ni * 16 + (lane & 15);                     // wave-local col
                Cw[lr * 64 + lc] = f2bf(acc[mi][ni][reg] + tl);
            }
    }
    #pragma unroll
    for (int s = 0; s < 8; ++s) {
        int row = s * 8 + (lane >> 3);
        int co = (lane & 7) * 8;
        int rl = rt * 128 + m0w + row;                              // chunk-local row
        int gb = b0 + n0w + co;
        *(int4*)&T[((size_t)rl * 256 + c) * 256 + gb] = *(int4*)&Cw[row * 64 + co];
    }
}

// ---------- stage2: merged U1/U2 (shared A), then V1(LDS)->P->dot ----------
// R1 layout, (256,2) = 2 blocks/CU (register-pinned: acc1+acc2 = 128 VGPRs).
// Both K-loops: FULLY-UNROLLED double-buffered single-barrier pipelines.
// After unroll every LDS base / global k-offset is a compile-time constant
// (R2's regression was runtime dbuf offsets: +VALU +spill). Prefetch(k+1)
// issues before ds_read+MFMA(k); the one barrier per step drains only
// residual latency. LDS: phase-A dbuf at 0/18432 (shorts); post-loop overlay:
// V1[0,16896) part[16896,17408); W3t dbuf at 18432/26624. Total 36864 sh = 73.7 KB.
__global__ __launch_bounds__(256, 2) void stage2(
    const short* __restrict__ l2b,
    const short* __restrict__ T1, const short* __restrict__ T2,
    const float* __restrict__ tail1, const float* __restrict__ tail2,
    const float* __restrict__ h1, const float* __restrict__ h2,
    const short* __restrict__ W3t, float* __restrict__ out, int row0)
{
    __shared__ __align__(16) short S2[36864];
    int t = threadIdx.x, w = t >> 6, lane = t & 63;
    int l4 = lane >> 2, kq = lane & 3;

    // --- bijective XCD-aware swizzle (nwg = 4*chunk, chunk pow2 -> %8==0) ---
    unsigned orig = blockIdx.x + (blockIdx.y << 2);
    unsigned nwg = gridDim.y << 2;
    unsigned swz = (orig & 7u) * (nwg >> 3) + (orig >> 3);
    int jt = swz & 3, rl = swz >> 2;

    int rg = row0 + rl, n = rg >> 8, j0 = jt * 64;
    const short* Arow = l2b + ((size_t)n * 256 + j0) * 256;
    const short* Tt1 = T1 + (size_t)rl * 65536;
    const short* Tt2 = T2 + (size_t)rl * 65536;
    int n0w = w * 64;

    // stage one 32-k slice of {A, B1, B2} into S2[base..base+18432)
    auto stageA = [&](int k0, int base) {
        #pragma unroll
        for (int q = 0; q < 9; ++q) {              // 4 Al + 16 B1 + 16 B2 = 36 segs
            int seg = w * 9 + q;
            const short* gb; short* lb;
            if (seg < 4)       { gb = Arow + (size_t)(seg * 16 + l4) * 256;        lb = &S2[base + seg * 512]; }
            else if (seg < 20) { int s = seg - 4;  gb = Tt1 + (size_t)(s * 16 + l4) * 256; lb = &S2[base + 2048 + s * 512]; }
            else               { int s = seg - 20; gb = Tt2 + (size_t)(s * 16 + l4) * 256; lb = &S2[base + 10240 + s * 512]; }
            gl16(gb + k0 + kq * 8, lb);
        }
    };

    // ---- phase A: U1 and U2 together (A shared), pipelined ----
    f32x4 acc1[4][4] = {}, acc2[4][4] = {};
    stageA(0, 0);
    __syncthreads();
    #pragma unroll
    for (int kt = 0; kt < 8; ++kt) {
        const int cur = (kt & 1) * 18432;          // compile-time after unroll
        if (kt < 7) stageA((kt + 1) * 32, cur ^ 18432);
        s16x8 af[4], b1[4], b2[4];
        #pragma unroll
        for (int i = 0; i < 4; ++i) {
            af[i] = *(const s16x8*)&S2[cur + (i * 16 + (lane & 15)) * 32 + (lane >> 4) * 8];
            b1[i] = *(const s16x8*)&S2[cur + 2048 + (n0w + i * 16 + (lane & 15)) * 32 + (lane >> 4) * 8];
            b2[i] = *(const s16x8*)&S2[cur + 10240 + (n0w + i * 16 + (lane & 15)) * 32 + (lane >> 4) * 8];
        }
        #pragma unroll
        for (int mi = 0; mi < 4; ++mi)
            #pragma unroll
            for (int ni = 0; ni < 4; ++ni) {
                acc1[mi][ni] = __builtin_amdgcn_mfma_f32_16x16x32_bf16(af[mi], b1[ni], acc1[mi][ni], 0, 0, 0);
                acc2[mi][ni] = __builtin_amdgcn_mfma_f32_16x16x32_bf16(af[mi], b2[ni], acc2[mi][ni], 0, 0, 0);
            }
        __syncthreads();   // drains next-tile loads + LDS reads; buffer swap safe
    }

    // V1 = h1*(U1+tail1) -> LDS bf16 (overlays phase-A buf0) ; v2 -> regs
    short* V1 = S2;                                // [64][264]
    f32x4 v2[4][4];
    #pragma unroll
    for (int ni = 0; ni < 4; ++ni) {
        int c = n0w + ni * 16 + (lane & 15);
        float hh1 = h1[(size_t)rg * 256 + c], tl1 = tail1[(size_t)rg * 256 + c];
        float hh2 = h2[(size_t)rg * 256 + c], tl2 = tail2[(size_t)rg * 256 + c];
        #pragma unroll
        for (int mi = 0; mi < 4; ++mi)
            #pragma unroll
            for (int reg = 0; reg < 4; ++reg) {
                int j = mi * 16 + (lane >> 4) * 4 + reg;
                V1[j * 264 + c] = f2bf(hh1 * (acc1[mi][ni][reg] + tl1));
                v2[mi][ni][reg] = hh2 * (acc2[mi][ni][reg] + tl2);
            }
    }

    // ---- phase B: P = V1 @ W3t^T, pipelined (W3t dbuf at 18432/26624) ----
    f32x4 accP[4][4] = {};
    #pragma unroll
    for (int q = 0; q < 4; ++q) {
        int s = w * 4 + q;
        gl16(W3t + (size_t)(s * 16 + l4) * 256 + kq * 8, &S2[18432 + s * 512]);
    }
    __syncthreads();   // covers V1 writes + W3t buf0 loads
    #pragma unroll
    for (int kt = 0; kt < 8; ++kt) {
        const int cur = 18432 + (kt & 1) * 8192;   // compile-time after unroll
        if (kt < 7) {
            const int nb = cur ^ 8192, k0n = (kt + 1) * 32;
            #pragma unroll
            for (int q = 0; q < 4; ++q) {
                int s = w * 4 + q;
                gl16(W3t + (size_t)(s * 16 + l4) * 256 + k0n + kq * 8, &S2[nb + s * 512]);
            }
        }
        const int k0c = kt * 32;
        s16x8 af[4], bf[4];
        #pragma unroll
        for (int i = 0; i < 4; ++i) {
            af[i] = *(const s16x8*)&V1[(i * 16 + (lane & 15)) * 264 + k0c + (lane >> 4) * 8];
            bf[i] = *(const s16x8*)&S2[cur + (n0w + i * 16 + (lane & 15)) * 32 + (lane >> 4) * 8];
        }
        #pragma unroll
        for (int mi = 0; mi < 4; ++mi)
            #pragma unroll
            for (int ni = 0; ni < 4; ++ni)
                accP[mi][ni] = __builtin_amdgcn_mfma_f32_16x16x32_bf16(af[mi], bf[ni], accP[mi][ni], 0, 0, 0);
        __syncthreads();
    }

    // out[j] = sum_d P[j][d] * V2[j][d]
    float* part = (float*)&S2[16896];              // disjoint from V1 and W3t bufs
    #pragma unroll
    for (int mi = 0; mi < 4; ++mi)
        #pragma unroll
        for (int reg = 0; reg < 4; ++reg) {
            float s = 0.f;
            #pragma unroll
            for (int ni = 0; ni < 4; ++ni) s += accP[mi][ni][reg] * v2[mi][ni][reg];
            s += __shfl_xor(s, 1); s += __shfl_xor(s, 2);
            s += __shfl_xor(s, 4); s += __shfl_xor(s, 8);
            if ((lane & 15) == 0)
                part[(mi * 16 + (lane >> 4) * 4 + reg) * 4 + w] = s;
        }
    __syncthreads();
    if (t < 64)
        out[(size_t)rg * 256 + j0 + t] = part[t*4] + part[t*4+1] + part[t*4+2] + part[t*4+3];
}

extern "C" void kernel_launch(void* const* d_in, const int* in_sizes, int n_in,
                              void* d_out, int out_size, void* d_ws, size_t ws_size,
                              hipStream_t stream) {
    const float* layer1 = (const float*)d_in[0];
    const float* layer2 = (const float*)d_in[1];
    const float* h1     = (const float*)d_in[2];
    const float* h2     = (const float*)d_in[3];
    const float* W1     = (const float*)d_in[4];
    const float* W2     = (const float*)d_in[5];
    const float* W3     = (const float*)d_in[6];
    float* out = (float*)d_out;

    short* Wp1  = (short*)d_ws;                  // 33.55 MB
    short* Wp2  = Wp1 + 16777216;
    short* l1b  = Wp2 + 16777216;                // 2048x256
    short* l2b  = l1b + 524288;
    short* W3t  = l2b + 524288;                  // 256x256
    short* Wtp1 = W3t + 65536;                   // 256x256
    short* Wtp2 = Wtp1 + 65536;
    float* tail1 = (float*)(Wtp2 + 65536);       // 2048x256 fp32
    float* tail2 = tail1 + 524288;
    short* T1   = (short*)(tail2 + 524288);
    const size_t head = (size_t)(16777216*2 + 524288*2 + 65536*3) * 2 + (size_t)524288 * 2 * 4;
    int chunk = 2048;
    while (head + (size_t)chunk * 262144 > ws_size && chunk > 128) chunk >>= 1;
    short* T2 = T1 + (size_t)chunk * 65536;

    conv_bf16<<<1024, 256, 0, stream>>>(layer1, layer2, l1b, l2b);
    prep_w3t<<<64, 256, 0, stream>>>(W3, W3t);
    prep_wtail<<<dim3(64, 2), 256, 0, stream>>>(W1, W2, Wtp1, Wtp2);
    prep_wp<<<dim3(64, 256, 2), 256, 0, stream>>>(W1, W2, Wp1, Wp2);
    tail_mfma<<<dim3(16, 2, 2), 256, 0, stream>>>(l1b, Wtp1, Wtp2, W1, W2, tail1, tail2);

    for (int row0 = 0; row0 < 2048; row0 += chunk) {
        stage1<<<dim3(chunk / 128, 2, 512), 256, 0, stream>>>(
            l1b, Wp1, Wp2, W1, W2, T1, T2, row0);
        stage2<<<dim3(4, chunk), 256, 0, stream>>>(
            l2b, T1, T2, tail1, tail2, h1, h2, W3t, out, row0);
    }
}

// Round 6
// 767.247 us; speedup vs baseline: 2.2169x; 1.0080x over previous
//
#include <hip/hip_runtime.h>

typedef __attribute__((ext_vector_type(4))) float f32x4;
typedef __attribute__((ext_vector_type(8))) short s16x8;

#define MTOTW 65792   // 257*256: fp32 W stride per a-index

__device__ __forceinline__ short f2bf(float f) {
    unsigned u = __builtin_bit_cast(unsigned, f);
    u = (u + 0x7fffu + ((u >> 16) & 1u)) >> 16;   // RNE
    return (short)u;
}

// async global->LDS, 16B per lane: LDS dest = uniform base + lane*16 (m97/m104)
__device__ __forceinline__ void gl16(const void* g, void* l) {
    __builtin_amdgcn_global_load_lds(
        (const __attribute__((address_space(1))) unsigned int*)g,
        (__attribute__((address_space(3))) unsigned int*)l, 16, 0, 0);
}

// ---------- prep: l1,l2 -> bf16 (flat) ----------
__global__ __launch_bounds__(256) void conv_bf16(
    const float* __restrict__ a, const float* __restrict__ b,
    short* __restrict__ ao, short* __restrict__ bo)
{
    int i = blockIdx.x * 256 + threadIdx.x;
    const int HALF = 131072;
    float4 v; short* dst;
    if (i < HALF) { v = ((const float4*)a)[i]; dst = ao + (size_t)i * 4; }
    else          { v = ((const float4*)b)[i - HALF]; dst = bo + (size_t)(i - HALF) * 4; }
    short4 o; o.x = f2bf(v.x); o.y = f2bf(v.y); o.z = f2bf(v.z); o.w = f2bf(v.w);
    *(short4*)dst = o;
}

// ---------- prep: W3t[d][c] = bf16(W3[c][d]) ----------
__global__ __launch_bounds__(256) void prep_w3t(
    const float* __restrict__ W3, short* __restrict__ W3t)
{
    __shared__ float ld[32][33];
    int t = threadIdx.x, bx = blockIdx.x;
    int c0 = (bx >> 3) * 32, d0 = (bx & 7) * 32;
    int cr = t >> 3, dq = t & 7;
    float4 v = *(const float4*)&W3[(size_t)(c0 + cr) * 256 + d0 + dq * 4];
    ld[cr][dq*4+0] = v.x; ld[cr][dq*4+1] = v.y; ld[cr][dq*4+2] = v.z; ld[cr][dq*4+3] = v.w;
    __syncthreads();
    int dr = t >> 3, cq = t & 7;
    short4 o;
    o.x = f2bf(ld[cq*4+0][dr]); o.y = f2bf(ld[cq*4+1][dr]);
    o.z = f2bf(ld[cq*4+2][dr]); o.w = f2bf(ld[cq*4+3][dr]);
    *(short4*)&W3t[(size_t)(d0 + dr) * 256 + c0 + cq * 4] = o;
}

// ---------- prep: Wtp[c][a] = bf16(W[a][256][c]) (the b=256 plane, transposed) ----------
__global__ __launch_bounds__(256) void prep_wtail(
    const float* __restrict__ W1, const float* __restrict__ W2,
    short* __restrict__ Wtp1, short* __restrict__ Wtp2)
{
    __shared__ float ld[32][33];
    int t = threadIdx.x, bx = blockIdx.x;
    const float* W = blockIdx.y ? W2 : W1;
    short* Wtp = blockIdx.y ? Wtp2 : Wtp1;
    int a0 = (bx >> 3) * 32, c0 = (bx & 7) * 32;
    int ar = t >> 3, cq = t & 7;
    float4 v = *(const float4*)&W[(size_t)(a0 + ar) * MTOTW + 65536 + c0 + cq * 4];
    ld[ar][cq*4+0] = v.x; ld[ar][cq*4+1] = v.y; ld[ar][cq*4+2] = v.z; ld[ar][cq*4+3] = v.w;
    __syncthreads();
    int cr = t >> 3, aq = t & 7;
    short4 o;
    o.x = f2bf(ld[aq*4+0][cr]); o.y = f2bf(ld[aq*4+1][cr]);
    o.z = f2bf(ld[aq*4+2][cr]); o.w = f2bf(ld[aq*4+3][cr]);
    *(short4*)&Wtp[(size_t)(c0 + cr) * 256 + a0 + aq * 4] = o;
}

// ---------- prep: Wp[c][b][a] = bf16(W[a][b][c]) ----------
__global__ __launch_bounds__(256) void prep_wp(
    const float* __restrict__ W1, const float* __restrict__ W2,
    short* __restrict__ Wp1, short* __restrict__ Wp2)
{
    __shared__ float ld[32][33];
    int t = threadIdx.x, bx = blockIdx.x;
    int b = blockIdx.y;
    const float* W = blockIdx.z ? W2 : W1;
    short* Wp = blockIdx.z ? Wp2 : Wp1;
    int a0 = (bx >> 3) * 32, c0 = (bx & 7) * 32;
    int ar = t >> 3, cq = t & 7;
    float4 v = *(const float4*)&W[(size_t)(a0 + ar) * MTOTW + (size_t)b * 256 + c0 + cq * 4];
    ld[ar][cq*4+0] = v.x; ld[ar][cq*4+1] = v.y; ld[ar][cq*4+2] = v.z; ld[ar][cq*4+3] = v.w;
    __syncthreads();
    int cr = t >> 3, aq = t & 7;
    short4 o;
    o.x = f2bf(ld[aq*4+0][cr]); o.y = f2bf(ld[aq*4+1][cr]);
    o.z = f2bf(ld[aq*4+2][cr]); o.w = f2bf(ld[aq*4+3][cr]);
    *(short4*)&Wp[((size_t)(c0 + cr) * 256 + b) * 256 + a0 + aq * 4] = o;
}

// ---------- tail_mfma: tail[r][c] = sum_{a<256} l1b[r][a]*Wtp[c][a] + W[256][256][c] ----------
__global__ __launch_bounds__(256, 2) void tail_mfma(
    const short* __restrict__ l1b,
    const short* __restrict__ Wtp1, const short* __restrict__ Wtp2,
    const float* __restrict__ W1, const float* __restrict__ W2,
    float* __restrict__ tail1, float* __restrict__ tail2)
{
    __shared__ __align__(16) short Al[128 * 32];
    __shared__ __align__(16) short Bl[128 * 32];
    int t = threadIdx.x, w = t >> 6, lane = t & 63;
    int l4 = lane >> 2, kq = lane & 3;
    int rt = blockIdx.x, nt = blockIdx.y, ten = blockIdx.z;
    const short* Wtp = ten ? Wtp2 : Wtp1;
    const float* Wf = ten ? W2 : W1;
    float* tail = ten ? tail2 : tail1;
    const short* Ab = l1b + (size_t)(rt * 128) * 256;
    const short* Bb = Wtp + (size_t)(nt * 128) * 256;

    f32x4 acc[4][4] = {};
    int m0w = (w >> 1) * 64, n0w = (w & 1) * 64;

    for (int k0 = 0; k0 < 256; k0 += 32) {
        __syncthreads();
        #pragma unroll
        for (int q = 0; q < 4; ++q) {
            int seg = w * 4 + q;
            if (seg < 8)
                gl16(Ab + (size_t)(seg * 16 + l4) * 256 + k0 + kq * 8, &Al[seg * 512]);
            else
                gl16(Bb + (size_t)((seg - 8) * 16 + l4) * 256 + k0 + kq * 8, &Bl[(seg - 8) * 512]);
        }
        __syncthreads();
        s16x8 af[4], bf[4];
        #pragma unroll
        for (int i = 0; i < 4; ++i) {
            af[i] = *(const s16x8*)&Al[(m0w + i * 16 + (lane & 15)) * 32 + (lane >> 4) * 8];
            bf[i] = *(const s16x8*)&Bl[(n0w + i * 16 + (lane & 15)) * 32 + (lane >> 4) * 8];
        }
        #pragma unroll
        for (int mi = 0; mi < 4; ++mi)
            #pragma unroll
            for (int ni = 0; ni < 4; ++ni)
                acc[mi][ni] = __builtin_amdgcn_mfma_f32_16x16x32_bf16(af[mi], bf[ni], acc[mi][ni], 0, 0, 0);
    }
    #pragma unroll
    for (int ni = 0; ni < 4; ++ni) {
        int c = nt * 128 + n0w + ni * 16 + (lane & 15);
        float tl = Wf[(size_t)256 * MTOTW + 65536 + c];   // a=256,b=256 term (coeff 1)
        #pragma unroll
        for (int mi = 0; mi < 4; ++mi) {
            int r = rt * 128 + m0w + mi * 16 + (lane >> 4) * 4;
            #pragma unroll
            for (int reg = 0; reg < 4; ++reg)
                tail[(size_t)(r + reg) * 256 + c] = acc[mi][ni][reg] + tl;
        }
    }
}

// ---------- stage1: T[rl][c][b] = bf16( sum_a l1b[r][a]*Wp[c][b][a] + W[256][b][c] ) ----------
// R5 winner, unchanged: serial 2-barrier K-steps + 32 KB LDS union, (256,3).
__global__ __launch_bounds__(256, 3) void stage1(
    const short* __restrict__ l1b,
    const short* __restrict__ Wp1, const short* __restrict__ Wp2,
    const float* __restrict__ W1, const float* __restrict__ W2,
    short* __restrict__ T1, short* __restrict__ T2, int row0)
{
    __shared__ __align__(16) short S[16384];   // union: {Al[0,4096)|Bl[4096,8192)} / Cep[0,16384)
    int t = threadIdx.x, w = t >> 6, lane = t & 63;
    int l4 = lane >> 2, kq = lane & 3;

    // --- bijective XCD-aware swizzle (nwg % 8 == 0 always: gdx*2*512) ---
    unsigned gdx = gridDim.x;                        // power of 2 (chunk/128)
    unsigned orig = blockIdx.x + gdx * (blockIdx.y + 2u * blockIdx.z);
    unsigned nwg = gdx * 1024u;
    unsigned swz = (orig & 7u) * (nwg >> 3) + (orig >> 3);
    int rt = swz & (gdx - 1u);
    unsigned rest = swz / gdx;
    int bt = rest & 1, zc = rest >> 1;

    int c = zc >> 1, ten = zc & 1;
    const short* Wp = ten ? Wp2 : Wp1;
    const float* Wf = ten ? W2 : W1;
    short* T = ten ? T2 : T1;
    int r0g = row0 + rt * 128;
    int b0 = bt * 128;
    const short* Ab = l1b + (size_t)r0g * 256;
    const short* Bb = Wp + ((size_t)c * 256 + b0) * 256;

    f32x4 acc[4][4] = {};
    int m0w = (w >> 1) * 64, n0w = (w & 1) * 64;

    for (int k0 = 0; k0 < 256; k0 += 32) {
        __syncthreads();
        #pragma unroll
        for (int q = 0; q < 4; ++q) {
            int seg = w * 4 + q;
            if (seg < 8)
                gl16(Ab + (size_t)(seg * 16 + l4) * 256 + k0 + kq * 8, &S[seg * 512]);
            else
                gl16(Bb + (size_t)((seg - 8) * 16 + l4) * 256 + k0 + kq * 8, &S[4096 + (seg - 8) * 512]);
        }
        __syncthreads();
        s16x8 af[4], bf[4];
        #pragma unroll
        for (int i = 0; i < 4; ++i) {
            af[i] = *(const s16x8*)&S[(m0w + i * 16 + (lane & 15)) * 32 + (lane >> 4) * 8];
            bf[i] = *(const s16x8*)&S[4096 + (n0w + i * 16 + (lane & 15)) * 32 + (lane >> 4) * 8];
        }
        #pragma unroll
        for (int mi = 0; mi < 4; ++mi)
            #pragma unroll
            for (int ni = 0; ni < 4; ++ni)
                acc[mi][ni] = __builtin_amdgcn_mfma_f32_16x16x32_bf16(af[mi], bf[ni], acc[mi][ni], 0, 0, 0);
    }
    __syncthreads();   // all waves done reading staging before Cep overlays it

    // epilogue: repack wave's 64x64 through LDS (per-wave region, no further sync)
    short* Cw = &S[w * 4096];
    #pragma unroll
    for (int ni = 0; ni < 4; ++ni) {
        int b = b0 + n0w + ni * 16 + (lane & 15);
        float tl = Wf[(size_t)256 * MTOTW + (size_t)b * 256 + c];   // a=256 tail, fp32
        #pragma unroll
        for (int mi = 0; mi < 4; ++mi)
            #pragma unroll
            for (int reg = 0; reg < 4; ++reg) {
                int lr = mi * 16 + (lane >> 4) * 4 + reg;           // wave-local row
                int lc = ni * 16 + (lane & 15);                     // wave-local col
                Cw[lr * 64 + lc] = f2bf(acc[mi][ni][reg] + tl);
            }
    }
    #pragma unroll
    for (int s = 0; s < 8; ++s) {
        int row = s * 8 + (lane >> 3);
        int co = (lane & 7) * 8;
        int rl = rt * 128 + m0w + row;                              // chunk-local row
        int gb = b0 + n0w + co;
        *(int4*)&T[((size_t)rl * 256 + c) * 256 + gb] = *(int4*)&Cw[row * 64 + co];
    }
}

// ---------- stage2: merged U1/U2 (shared A), then V1(LDS)->P->dot ----------
// R1 serial 2-barrier schedule (the proven-best schedule) + 52 KB LDS layout
// so HW occupancy rises to 3 blocks/CU. launch_bounds STAYS (256,2): R4 showed
// (256,3) makes the allocator spill the dual accumulators (527 MB scratch);
// at (256,2) the kernel compiles to ~112 VGPR (<=128 -> 4 waves/SIMD possible),
// so occupancy = min(LDS 3, VGPR 4) = 3 blocks/CU.
//   phase A: Al[0,2048) | B1l[2048,10240) | B2l[10240,18432)  (shorts)
//   then:    V1[0,16896) | part[16896,17408) | W3t-staging[18432,26624)
__global__ __launch_bounds__(256, 2) void stage2(
    const short* __restrict__ l2b,
    const short* __restrict__ T1, const short* __restrict__ T2,
    const float* __restrict__ tail1, const float* __restrict__ tail2,
    const float* __restrict__ h1, const float* __restrict__ h2,
    const short* __restrict__ W3t, float* __restrict__ out, int row0)
{
    __shared__ __align__(16) short S2[26624];   // 52 KB
    int t = threadIdx.x, w = t >> 6, lane = t & 63;
    int l4 = lane >> 2, kq = lane & 3;

    // --- bijective XCD-aware swizzle (nwg = 4*chunk, chunk pow2 -> %8==0) ---
    unsigned orig = blockIdx.x + (blockIdx.y << 2);
    unsigned nwg = gridDim.y << 2;
    unsigned swz = (orig & 7u) * (nwg >> 3) + (orig >> 3);
    int jt = swz & 3, rl = swz >> 2;

    int rg = row0 + rl, n = rg >> 8, j0 = jt * 64;
    const short* Arow = l2b + ((size_t)n * 256 + j0) * 256;
    const short* Tt1 = T1 + (size_t)rl * 65536;
    const short* Tt2 = T2 + (size_t)rl * 65536;
    int n0w = w * 64;

    // ---- phase A: U1 and U2 together (A shared) ----
    f32x4 acc1[4][4] = {}, acc2[4][4] = {};
    for (int k0 = 0; k0 < 256; k0 += 32) {
        __syncthreads();
        #pragma unroll
        for (int q = 0; q < 9; ++q) {              // 4 Al + 16 B1 + 16 B2 = 36 segs
            int seg = w * 9 + q;
            const short* gb; short* lb;
            if (seg < 4)       { gb = Arow + (size_t)(seg * 16 + l4) * 256;        lb = &S2[seg * 512]; }
            else if (seg < 20) { int s = seg - 4;  gb = Tt1 + (size_t)(s * 16 + l4) * 256; lb = &S2[2048 + s * 512]; }
            else               { int s = seg - 20; gb = Tt2 + (size_t)(s * 16 + l4) * 256; lb = &S2[10240 + s * 512]; }
            gl16(gb + k0 + kq * 8, lb);
        }
        __syncthreads();
        s16x8 af[4], b1[4], b2[4];
        #pragma unroll
        for (int i = 0; i < 4; ++i) {
            af[i] = *(const s16x8*)&S2[(i * 16 + (lane & 15)) * 32 + (lane >> 4) * 8];
            b1[i] = *(const s16x8*)&S2[2048 + (n0w + i * 16 + (lane & 15)) * 32 + (lane >> 4) * 8];
            b2[i] = *(const s16x8*)&S2[10240 + (n0w + i * 16 + (lane & 15)) * 32 + (lane >> 4) * 8];
        }
        #pragma unroll
        for (int mi = 0; mi < 4; ++mi)
            #pragma unroll
            for (int ni = 0; ni < 4; ++ni) {
                acc1[mi][ni] = __builtin_amdgcn_mfma_f32_16x16x32_bf16(af[mi], b1[ni], acc1[mi][ni], 0, 0, 0);
                acc2[mi][ni] = __builtin_amdgcn_mfma_f32_16x16x32_bf16(af[mi], b2[ni], acc2[mi][ni], 0, 0, 0);
            }
    }
    __syncthreads();   // all waves done reading phase-A staging before V1 overlays it

    // V1 = h1*(U1+tail1) -> LDS bf16 ; v2 = h2*(U2+tail2) -> regs
    short* V1 = S2;                                  // [64][264], overlays phase-A bufs
    f32x4 v2[4][4];
    #pragma unroll
    for (int ni = 0; ni < 4; ++ni) {
        int c = n0w + ni * 16 + (lane & 15);
        float hh1 = h1[(size_t)rg * 256 + c], tl1 = tail1[(size_t)rg * 256 + c];
        float hh2 = h2[(size_t)rg * 256 + c], tl2 = tail2[(size_t)rg * 256 + c];
        #pragma unroll
        for (int mi = 0; mi < 4; ++mi)
            #pragma unroll
            for (int reg = 0; reg < 4; ++reg) {
                int j = mi * 16 + (lane >> 4) * 4 + reg;
                V1[j * 264 + c] = f2bf(hh1 * (acc1[mi][ni][reg] + tl1));
                v2[mi][ni][reg] = hh2 * (acc2[mi][ni][reg] + tl2);
            }
    }
    __syncthreads();   // V1 visible to all waves

    // ---- phase B: P = V1 @ W3t^T (A from V1-LDS, B=W3t staged at S2[18432..26624)) ----
    f32x4 accP[4][4] = {};
    for (int k0 = 0; k0 < 256; k0 += 32) {
        __syncthreads();
        #pragma unroll
        for (int q = 0; q < 4; ++q) {
            int s = w * 4 + q;
            gl16(W3t + (size_t)(s * 16 + l4) * 256 + k0 + kq * 8, &S2[18432 + s * 512]);
        }
        __syncthreads();
        s16x8 af[4], bf[4];
        #pragma unroll
        for (int i = 0; i < 4; ++i) {
            af[i] = *(const s16x8*)&V1[(i * 16 + (lane & 15)) * 264 + k0 + (lane >> 4) * 8];
            bf[i] = *(const s16x8*)&S2[18432 + (n0w + i * 16 + (lane & 15)) * 32 + (lane >> 4) * 8];
        }
        #pragma unroll
        for (int mi = 0; mi < 4; ++mi)
            #pragma unroll
            for (int ni = 0; ni < 4; ++ni)
                accP[mi][ni] = __builtin_amdgcn_mfma_f32_16x16x32_bf16(af[mi], bf[ni], accP[mi][ni], 0, 0, 0);
    }

    // out[j] = sum_d P[j][d] * V2[j][d]
    float* part = (float*)&S2[16896];                // disjoint from V1 and W3t staging
    #pragma unroll
    for (int mi = 0; mi < 4; ++mi)
        #pragma unroll
        for (int reg = 0; reg < 4; ++reg) {
            float s = 0.f;
            #pragma unroll
            for (int ni = 0; ni < 4; ++ni) s += accP[mi][ni][reg] * v2[mi][ni][reg];
            s += __shfl_xor(s, 1); s += __shfl_xor(s, 2);
            s += __shfl_xor(s, 4); s += __shfl_xor(s, 8);
            if ((lane & 15) == 0)
                part[(mi * 16 + (lane >> 4) * 4 + reg) * 4 + w] = s;
        }
    __syncthreads();
    if (t < 64)
        out[(size_t)rg * 256 + j0 + t] = part[t*4] + part[t*4+1] + part[t*4+2] + part[t*4+3];
}

extern "C" void kernel_launch(void* const* d_in, const int* in_sizes, int n_in,
                              void* d_out, int out_size, void* d_ws, size_t ws_size,
                              hipStream_t stream) {
    const float* layer1 = (const float*)d_in[0];
    const float* layer2 = (const float*)d_in[1];
    const float* h1     = (const float*)d_in[2];
    const float* h2     = (const float*)d_in[3];
    const float* W1     = (const float*)d_in[4];
    const float* W2     = (const float*)d_in[5];
    const float* W3     = (const float*)d_in[6];
    float* out = (float*)d_out;

    short* Wp1  = (short*)d_ws;                  // 33.55 MB
    short* Wp2  = Wp1 + 16777216;
    short* l1b  = Wp2 + 16777216;                // 2048x256
    short* l2b  = l1b + 524288;
    short* W3t  = l2b + 524288;                  // 256x256
    short* Wtp1 = W3t + 65536;                   // 256x256
    short* Wtp2 = Wtp1 + 65536;
    float* tail1 = (float*)(Wtp2 + 65536);       // 2048x256 fp32
    float* tail2 = tail1 + 524288;
    short* T1   = (short*)(tail2 + 524288);
    const size_t head = (size_t)(16777216*2 + 524288*2 + 65536*3) * 2 + (size_t)524288 * 2 * 4;
    int chunk = 2048;
    while (head + (size_t)chunk * 262144 > ws_size && chunk > 128) chunk >>= 1;
    short* T2 = T1 + (size_t)chunk * 65536;

    conv_bf16<<<1024, 256, 0, stream>>>(layer1, layer2, l1b, l2b);
    prep_w3t<<<64, 256, 0, stream>>>(W3, W3t);
    prep_wtail<<<dim3(64, 2), 256, 0, stream>>>(W1, W2, Wtp1, Wtp2);
    prep_wp<<<dim3(64, 256, 2), 256, 0, stream>>>(W1, W2, Wp1, Wp2);
    tail_mfma<<<dim3(16, 2, 2), 256, 0, stream>>>(l1b, Wtp1, Wtp2, W1, W2, tail1, tail2);

    for (int row0 = 0; row0 < 2048; row0 += chunk) {
        stage1<<<dim3(chunk / 128, 2, 512), 256, 0, stream>>>(
            l1b, Wp1, Wp2, W1, W2, T1, T2, row0);
        stage2<<<dim3(4, chunk), 256, 0, stream>>>(
            l2b, T1, T2, tail1, tail2, h1, h2, W3t, out, row0);
    }
}

// Round 7
// 725.258 us; speedup vs baseline: 2.3452x; 1.0579x over previous
//
#include <hip/hip_runtime.h>

typedef __attribute__((ext_vector_type(4))) float f32x4;
typedef __attribute__((ext_vector_type(8))) short s16x8;

#define MTOTW 65792   // 257*256: fp32 W stride per a-index

__device__ __forceinline__ short f2bf(float f) {
    unsigned u = __builtin_bit_cast(unsigned, f);
    u = (u + 0x7fffu + ((u >> 16) & 1u)) >> 16;   // RNE
    return (short)u;
}

// async global->LDS, 16B per lane: LDS dest = uniform base + lane*16 (m97/m104)
__device__ __forceinline__ void gl16(const void* g, void* l) {
    __builtin_amdgcn_global_load_lds(
        (const __attribute__((address_space(1))) unsigned int*)g,
        (__attribute__((address_space(3))) unsigned int*)l, 16, 0, 0);
}

// ---- BK=64 swizzled tiles -----------------------------------------------
// Tile = [rows][64 shorts] (128 B/row = 8 x 16B chunks). gl16 dest linear;
// global source chunk is XORed by row&7; reads XOR the same way (involution,
// rule #21: both-sides-or-neither). LDS[r][p] holds global chunk p^(r&7);
// to read global chunk g of row r -> slot g^(r&7). Lanes 0-15 of a b128
// fragment read hit all 8 slots (2 lanes/slot = conflict-free, m136).

// ---------- prep: l1,l2 -> bf16 (flat) ----------
__global__ __launch_bounds__(256) void conv_bf16(
    const float* __restrict__ a, const float* __restrict__ b,
    short* __restrict__ ao, short* __restrict__ bo)
{
    int i = blockIdx.x * 256 + threadIdx.x;
    const int HALF = 131072;
    float4 v; short* dst;
    if (i < HALF) { v = ((const float4*)a)[i]; dst = ao + (size_t)i * 4; }
    else          { v = ((const float4*)b)[i - HALF]; dst = bo + (size_t)(i - HALF) * 4; }
    short4 o; o.x = f2bf(v.x); o.y = f2bf(v.y); o.z = f2bf(v.z); o.w = f2bf(v.w);
    *(short4*)dst = o;
}

// ---------- prep: W3t[d][c] = bf16(W3[c][d]) ----------
__global__ __launch_bounds__(256) void prep_w3t(
    const float* __restrict__ W3, short* __restrict__ W3t)
{
    __shared__ float ld[32][33];
    int t = threadIdx.x, bx = blockIdx.x;
    int c0 = (bx >> 3) * 32, d0 = (bx & 7) * 32;
    int cr = t >> 3, dq = t & 7;
    float4 v = *(const float4*)&W3[(size_t)(c0 + cr) * 256 + d0 + dq * 4];
    ld[cr][dq*4+0] = v.x; ld[cr][dq*4+1] = v.y; ld[cr][dq*4+2] = v.z; ld[cr][dq*4+3] = v.w;
    __syncthreads();
    int dr = t >> 3, cq = t & 7;
    short4 o;
    o.x = f2bf(ld[cq*4+0][dr]); o.y = f2bf(ld[cq*4+1][dr]);
    o.z = f2bf(ld[cq*4+2][dr]); o.w = f2bf(ld[cq*4+3][dr]);
    *(short4*)&W3t[(size_t)(d0 + dr) * 256 + c0 + cq * 4] = o;
}

// ---------- prep: Wtp[c][a] = bf16(W[a][256][c]) (the b=256 plane, transposed) ----------
__global__ __launch_bounds__(256) void prep_wtail(
    const float* __restrict__ W1, const float* __restrict__ W2,
    short* __restrict__ Wtp1, short* __restrict__ Wtp2)
{
    __shared__ float ld[32][33];
    int t = threadIdx.x, bx = blockIdx.x;
    const float* W = blockIdx.y ? W2 : W1;
    short* Wtp = blockIdx.y ? Wtp2 : Wtp1;
    int a0 = (bx >> 3) * 32, c0 = (bx & 7) * 32;
    int ar = t >> 3, cq = t & 7;
    float4 v = *(const float4*)&W[(size_t)(a0 + ar) * MTOTW + 65536 + c0 + cq * 4];
    ld[ar][cq*4+0] = v.x; ld[ar][cq*4+1] = v.y; ld[ar][cq*4+2] = v.z; ld[ar][cq*4+3] = v.w;
    __syncthreads();
    int cr = t >> 3, aq = t & 7;
    short4 o;
    o.x = f2bf(ld[aq*4+0][cr]); o.y = f2bf(ld[aq*4+1][cr]);
    o.z = f2bf(ld[aq*4+2][cr]); o.w = f2bf(ld[aq*4+3][cr]);
    *(short4*)&Wtp[(size_t)(c0 + cr) * 256 + a0 + aq * 4] = o;
}

// ---------- prep: Wp[c][b][a] = bf16(W[a][b][c]) ----------
__global__ __launch_bounds__(256) void prep_wp(
    const float* __restrict__ W1, const float* __restrict__ W2,
    short* __restrict__ Wp1, short* __restrict__ Wp2)
{
    __shared__ float ld[32][33];
    int t = threadIdx.x, bx = blockIdx.x;
    int b = blockIdx.y;
    const float* W = blockIdx.z ? W2 : W1;
    short* Wp = blockIdx.z ? Wp2 : Wp1;
    int a0 = (bx >> 3) * 32, c0 = (bx & 7) * 32;
    int ar = t >> 3, cq = t & 7;
    float4 v = *(const float4*)&W[(size_t)(a0 + ar) * MTOTW + (size_t)b * 256 + c0 + cq * 4];
    ld[ar][cq*4+0] = v.x; ld[ar][cq*4+1] = v.y; ld[ar][cq*4+2] = v.z; ld[ar][cq*4+3] = v.w;
    __syncthreads();
    int cr = t >> 3, aq = t & 7;
    short4 o;
    o.x = f2bf(ld[aq*4+0][cr]); o.y = f2bf(ld[aq*4+1][cr]);
    o.z = f2bf(ld[aq*4+2][cr]); o.w = f2bf(ld[aq*4+3][cr]);
    *(short4*)&Wp[((size_t)(c0 + cr) * 256 + b) * 256 + a0 + aq * 4] = o;
}

// ---------- tail_mfma: unchanged (small, one-shot) ----------
__global__ __launch_bounds__(256, 2) void tail_mfma(
    const short* __restrict__ l1b,
    const short* __restrict__ Wtp1, const short* __restrict__ Wtp2,
    const float* __restrict__ W1, const float* __restrict__ W2,
    float* __restrict__ tail1, float* __restrict__ tail2)
{
    __shared__ __align__(16) short Al[128 * 32];
    __shared__ __align__(16) short Bl[128 * 32];
    int t = threadIdx.x, w = t >> 6, lane = t & 63;
    int l4 = lane >> 2, kq = lane & 3;
    int rt = blockIdx.x, nt = blockIdx.y, ten = blockIdx.z;
    const short* Wtp = ten ? Wtp2 : Wtp1;
    const float* Wf = ten ? W2 : W1;
    float* tail = ten ? tail2 : tail1;
    const short* Ab = l1b + (size_t)(rt * 128) * 256;
    const short* Bb = Wtp + (size_t)(nt * 128) * 256;

    f32x4 acc[4][4] = {};
    int m0w = (w >> 1) * 64, n0w = (w & 1) * 64;

    for (int k0 = 0; k0 < 256; k0 += 32) {
        __syncthreads();
        #pragma unroll
        for (int q = 0; q < 4; ++q) {
            int seg = w * 4 + q;
            if (seg < 8)
                gl16(Ab + (size_t)(seg * 16 + l4) * 256 + k0 + kq * 8, &Al[seg * 512]);
            else
                gl16(Bb + (size_t)((seg - 8) * 16 + l4) * 256 + k0 + kq * 8, &Bl[(seg - 8) * 512]);
        }
        __syncthreads();
        s16x8 af[4], bf[4];
        #pragma unroll
        for (int i = 0; i < 4; ++i) {
            af[i] = *(const s16x8*)&Al[(m0w + i * 16 + (lane & 15)) * 32 + (lane >> 4) * 8];
            bf[i] = *(const s16x8*)&Bl[(n0w + i * 16 + (lane & 15)) * 32 + (lane >> 4) * 8];
        }
        #pragma unroll
        for (int mi = 0; mi < 4; ++mi)
            #pragma unroll
            for (int ni = 0; ni < 4; ++ni)
                acc[mi][ni] = __builtin_amdgcn_mfma_f32_16x16x32_bf16(af[mi], bf[ni], acc[mi][ni], 0, 0, 0);
    }
    #pragma unroll
    for (int ni = 0; ni < 4; ++ni) {
        int c = nt * 128 + n0w + ni * 16 + (lane & 15);
        float tl = Wf[(size_t)256 * MTOTW + 65536 + c];   // a=256,b=256 term (coeff 1)
        #pragma unroll
        for (int mi = 0; mi < 4; ++mi) {
            int r = rt * 128 + m0w + mi * 16 + (lane >> 4) * 4;
            #pragma unroll
            for (int reg = 0; reg < 4; ++reg)
                tail[(size_t)(r + reg) * 256 + c] = acc[mi][ni][reg] + tl;
        }
    }
}

// ---------- stage1: T[rl][c][b] = bf16( sum_a l1b[r][a]*Wp[c][b][a] + W[256][b][c] ) ----------
// BK=64: 4 K-steps (half the barrier drains), swizzled tiles (conflict-free
// ds_read_b128). LDS 32 KB total: {A[0,8192)|B[8192,16384)} shorts, Cep overlay.
__global__ __launch_bounds__(256, 3) void stage1(
    const short* __restrict__ l1b,
    const short* __restrict__ Wp1, const short* __restrict__ Wp2,
    const float* __restrict__ W1, const float* __restrict__ W2,
    short* __restrict__ T1, short* __restrict__ T2, int row0)
{
    __shared__ __align__(16) short S[16384];
    int t = threadIdx.x, w = t >> 6, lane = t & 63;
    int srow8 = lane >> 3;                       // row-within-seg (0..7)
    int sch   = (lane & 7) ^ srow8;              // swizzled source chunk
    int fr    = lane & 15, fb7 = lane & 7;

    // --- bijective XCD-aware swizzle (nwg % 8 == 0 always: gdx*2*512) ---
    unsigned gdx = gridDim.x;                    // power of 2 (chunk/128)
    unsigned orig = blockIdx.x + gdx * (blockIdx.y + 2u * blockIdx.z);
    unsigned nwg = gdx * 1024u;
    unsigned swz = (orig & 7u) * (nwg >> 3) + (orig >> 3);
    int rt = swz & (gdx - 1u);
    unsigned rest = swz / gdx;
    int bt = rest & 1, zc = rest >> 1;

    int c = zc >> 1, ten = zc & 1;
    const short* Wp = ten ? Wp2 : Wp1;
    const float* Wf = ten ? W2 : W1;
    short* T = ten ? T2 : T1;
    int r0g = row0 + rt * 128;
    int b0 = bt * 128;
    const short* Ab = l1b + (size_t)r0g * 256;
    const short* Bb = Wp + ((size_t)c * 256 + b0) * 256;

    f32x4 acc[4][4] = {};
    int m0w = (w >> 1) * 64, n0w = (w & 1) * 64;

    for (int kt = 0; kt < 4; ++kt) {
        int k0 = kt * 64;
        __syncthreads();
        #pragma unroll
        for (int q = 0; q < 8; ++q) {            // 16 A segs + 16 B segs, 8/wave
            int seg = w * 8 + q;
            int rloc = (seg & 15) * 8 + srow8;   // tile row 0..127
            const short* gb = (seg < 16) ? Ab : Bb;
            gl16(gb + (size_t)rloc * 256 + k0 + sch * 8, &S[seg * 512]);
        }
        __syncthreads();
        #pragma unroll
        for (int ss = 0; ss < 2; ++ss) {
            int cx = ((ss * 4 + (lane >> 4)) ^ fb7) * 8;
            s16x8 af[4], bf[4];
            #pragma unroll
            for (int i = 0; i < 4; ++i) {
                af[i] = *(const s16x8*)&S[(m0w + i * 16 + fr) * 64 + cx];
                bf[i] = *(const s16x8*)&S[8192 + (n0w + i * 16 + fr) * 64 + cx];
            }
            #pragma unroll
            for (int mi = 0; mi < 4; ++mi)
                #pragma unroll
                for (int ni = 0; ni < 4; ++ni)
                    acc[mi][ni] = __builtin_amdgcn_mfma_f32_16x16x32_bf16(af[mi], bf[ni], acc[mi][ni], 0, 0, 0);
        }
    }
    __syncthreads();   // all waves done reading staging before Cep overlays it

    // epilogue: repack wave's 64x64 through LDS (per-wave region, no further sync)
    short* Cw = &S[w * 4096];
    #pragma unroll
    for (int ni = 0; ni < 4; ++ni) {
        int b = b0 + n0w + ni * 16 + (lane & 15);
        float tl = Wf[(size_t)256 * MTOTW + (size_t)b * 256 + c];   // a=256 tail, fp32
        #pragma unroll
        for (int mi = 0; mi < 4; ++mi)
            #pragma unroll
            for (int reg = 0; reg < 4; ++reg) {
                int lr = mi * 16 + (lane >> 4) * 4 + reg;           // wave-local row
                int lc = ni * 16 + (lane & 15);                     // wave-local col
                Cw[lr * 64 + lc] = f2bf(acc[mi][ni][reg] + tl);
            }
    }
    #pragma unroll
    for (int s = 0; s < 8; ++s) {
        int row = s * 8 + (lane >> 3);
        int co = (lane & 7) * 8;
        int rl = rt * 128 + m0w + row;                              // chunk-local row
        int gb = b0 + n0w + co;
        *(int4*)&T[((size_t)rl * 256 + c) * 256 + gb] = *(int4*)&Cw[row * 64 + co];
    }
}

// ---------- stage2: merged U1/U2 (shared A), then V1(LDS)->P->dot ----------
// BK=64 + swizzled tiles. Register-pinned at 2 blocks/CU (acc1+acc2 AGPRs),
// so LDS is free: staging Al[0,4096)|B1l[4096,20480)|B2l[20480,36864) shorts.
// Overlay post-A: V1[0,16896) | part[16896,17408) | W3t tile[20480,36864).
__global__ __launch_bounds__(256, 2) void stage2(
    const short* __restrict__ l2b,
    const short* __restrict__ T1, const short* __restrict__ T2,
    const float* __restrict__ tail1, const float* __restrict__ tail2,
    const float* __restrict__ h1, const float* __restrict__ h2,
    const short* __restrict__ W3t, float* __restrict__ out, int row0)
{
    __shared__ __align__(16) short S2[36864];   // 72 KB
    int t = threadIdx.x, w = t >> 6, lane = t & 63;
    int srow8 = lane >> 3;
    int sch   = (lane & 7) ^ srow8;
    int fr    = lane & 15, fb7 = lane & 7;

    // --- bijective XCD-aware swizzle (nwg = 4*chunk, chunk pow2 -> %8==0) ---
    unsigned orig = blockIdx.x + (blockIdx.y << 2);
    unsigned nwg = gridDim.y << 2;
    unsigned swz = (orig & 7u) * (nwg >> 3) + (orig >> 3);
    int jt = swz & 3, rl = swz >> 2;

    int rg = row0 + rl, n = rg >> 8, j0 = jt * 64;
    const short* Arow = l2b + ((size_t)n * 256 + j0) * 256;
    const short* Tt1 = T1 + (size_t)rl * 65536;
    const short* Tt2 = T2 + (size_t)rl * 65536;
    int n0w = w * 64;

    // ---- phase A: U1 and U2 together (A shared), BK=64 ----
    f32x4 acc1[4][4] = {}, acc2[4][4] = {};
    for (int kt = 0; kt < 4; ++kt) {
        int k0 = kt * 64;
        __syncthreads();
        #pragma unroll
        for (int q = 0; q < 18; ++q) {           // 8 Al + 32 B1 + 32 B2 = 72 segs
            int seg = w * 18 + q;
            const short* gb; short* lb; int rloc;
            if (seg < 8)       { rloc = seg * 8 + srow8;        gb = Arow; lb = &S2[seg * 512]; }
            else if (seg < 40) { rloc = (seg - 8) * 8 + srow8;  gb = Tt1;  lb = &S2[4096 + (seg - 8) * 512]; }
            else               { rloc = (seg - 40) * 8 + srow8; gb = Tt2;  lb = &S2[20480 + (seg - 40) * 512]; }
            gl16(gb + (size_t)rloc * 256 + k0 + sch * 8, lb);
        }
        __syncthreads();
        #pragma unroll
        for (int ss = 0; ss < 2; ++ss) {
            int cx = ((ss * 4 + (lane >> 4)) ^ fb7) * 8;
            s16x8 af[4], b1[4], b2[4];
            #pragma unroll
            for (int i = 0; i < 4; ++i) {
                af[i] = *(const s16x8*)&S2[(i * 16 + fr) * 64 + cx];
                b1[i] = *(const s16x8*)&S2[4096 + (n0w + i * 16 + fr) * 64 + cx];
                b2[i] = *(const s16x8*)&S2[20480 + (n0w + i * 16 + fr) * 64 + cx];
            }
            #pragma unroll
            for (int mi = 0; mi < 4; ++mi)
                #pragma unroll
                for (int ni = 0; ni < 4; ++ni) {
                    acc1[mi][ni] = __builtin_amdgcn_mfma_f32_16x16x32_bf16(af[mi], b1[ni], acc1[mi][ni], 0, 0, 0);
                    acc2[mi][ni] = __builtin_amdgcn_mfma_f32_16x16x32_bf16(af[mi], b2[ni], acc2[mi][ni], 0, 0, 0);
                }
        }
    }
    __syncthreads();   // staging reads complete before V1 overlays

    // V1 = h1*(U1+tail1) -> LDS bf16 ; v2 = h2*(U2+tail2) -> regs
    short* V1 = S2;                              // [64][264], overlays Al/B1l
    f32x4 v2[4][4];
    #pragma unroll
    for (int ni = 0; ni < 4; ++ni) {
        int c = n0w + ni * 16 + (lane & 15);
        float hh1 = h1[(size_t)rg * 256 + c], tl1 = tail1[(size_t)rg * 256 + c];
        float hh2 = h2[(size_t)rg * 256 + c], tl2 = tail2[(size_t)rg * 256 + c];
        #pragma unroll
        for (int mi = 0; mi < 4; ++mi)
            #pragma unroll
            for (int reg = 0; reg < 4; ++reg) {
                int j = mi * 16 + (lane >> 4) * 4 + reg;
                V1[j * 264 + c] = f2bf(hh1 * (acc1[mi][ni][reg] + tl1));
                v2[mi][ni][reg] = hh2 * (acc2[mi][ni][reg] + tl2);
            }
    }
    __syncthreads();   // V1 visible

    // ---- phase B: P = V1 @ W3t^T, BK=64 (W3t tile at [20480,36864), swizzled) ----
    f32x4 accP[4][4] = {};
    for (int kt = 0; kt < 4; ++kt) {
        int k0 = kt * 64;
        __syncthreads();
        #pragma unroll
        for (int q = 0; q < 8; ++q) {            // 32 segs of W3t 256x64
            int seg = w * 8 + q;
            int rloc = seg * 8 + srow8;
            gl16(W3t + (size_t)rloc * 256 + k0 + sch * 8, &S2[20480 + seg * 512]);
        }
        __syncthreads();
        #pragma unroll
        for (int ss = 0; ss < 2; ++ss) {
            int cx = ((ss * 4 + (lane >> 4)) ^ fb7) * 8;
            s16x8 af[4], bf[4];
            #pragma unroll
            for (int i = 0; i < 4; ++i) {
                af[i] = *(const s16x8*)&V1[(i * 16 + fr) * 264 + k0 + ss * 32 + (lane >> 4) * 8];
                bf[i] = *(const s16x8*)&S2[20480 + (n0w + i * 16 + fr) * 64 + cx];
            }
            #pragma unroll
            for (int mi = 0; mi < 4; ++mi)
                #pragma unroll
                for (int ni = 0; ni < 4; ++ni)
                    accP[mi][ni] = __builtin_amdgcn_mfma_f32_16x16x32_bf16(af[mi], bf[ni], accP[mi][ni], 0, 0, 0);
        }
    }

    // out[j] = sum_d P[j][d] * V2[j][d]
    float* part = (float*)&S2[16896];            // disjoint from V1 and W3t tile
    #pragma unroll
    for (int mi = 0; mi < 4; ++mi)
        #pragma unroll
        for (int reg = 0; reg < 4; ++reg) {
            float s = 0.f;
            #pragma unroll
            for (int ni = 0; ni < 4; ++ni) s += accP[mi][ni][reg] * v2[mi][ni][reg];
            s += __shfl_xor(s, 1); s += __shfl_xor(s, 2);
            s += __shfl_xor(s, 4); s += __shfl_xor(s, 8);
            if ((lane & 15) == 0)
                part[(mi * 16 + (lane >> 4) * 4 + reg) * 4 + w] = s;
        }
    __syncthreads();
    if (t < 64)
        out[(size_t)rg * 256 + j0 + t] = part[t*4] + part[t*4+1] + part[t*4+2] + part[t*4+3];
}

extern "C" void kernel_launch(void* const* d_in, const int* in_sizes, int n_in,
                              void* d_out, int out_size, void* d_ws, size_t ws_size,
                              hipStream_t stream) {
    const float* layer1 = (const float*)d_in[0];
    const float* layer2 = (const float*)d_in[1];
    const float* h1     = (const float*)d_in[2];
    const float* h2     = (const float*)d_in[3];
    const float* W1     = (const float*)d_in[4];
    const float* W2     = (const float*)d_in[5];
    const float* W3     = (const float*)d_in[6];
    float* out = (float*)d_out;

    short* Wp1  = (short*)d_ws;                  // 33.55 MB
    short* Wp2  = Wp1 + 16777216;
    short* l1b  = Wp2 + 16777216;                // 2048x256
    short* l2b  = l1b + 524288;
    short* W3t  = l2b + 524288;                  // 256x256
    short* Wtp1 = W3t + 65536;                   // 256x256
    short* Wtp2 = Wtp1 + 65536;
    float* tail1 = (float*)(Wtp2 + 65536);       // 2048x256 fp32
    float* tail2 = tail1 + 524288;
    short* T1   = (short*)(tail2 + 524288);
    const size_t head = (size_t)(16777216*2 + 524288*2 + 65536*3) * 2 + (size_t)524288 * 2 * 4;
    int chunk = 2048;
    while (head + (size_t)chunk * 262144 > ws_size && chunk > 128) chunk >>= 1;
    short* T2 = T1 + (size_t)chunk * 65536;

    conv_bf16<<<1024, 256, 0, stream>>>(layer1, layer2, l1b, l2b);
    prep_w3t<<<64, 256, 0, stream>>>(W3, W3t);
    prep_wtail<<<dim3(64, 2), 256, 0, stream>>>(W1, W2, Wtp1, Wtp2);
    prep_wp<<<dim3(64, 256, 2), 256, 0, stream>>>(W1, W2, Wp1, Wp2);
    tail_mfma<<<dim3(16, 2, 2), 256, 0, stream>>>(l1b, Wtp1, Wtp2, W1, W2, tail1, tail2);

    for (int row0 = 0; row0 < 2048; row0 += chunk) {
        stage1<<<dim3(chunk / 128, 2, 512), 256, 0, stream>>>(
            l1b, Wp1, Wp2, W1, W2, T1, T2, row0);
        stage2<<<dim3(4, chunk), 256, 0, stream>>>(
            l2b, T1, T2, tail1, tail2, h1, h2, W3t, out, row0);
    }
}

// Round 8
// 680.092 us; speedup vs baseline: 2.5010x; 1.0664x over previous
//
#include <hip/hip_runtime.h>

typedef __attribute__((ext_vector_type(4))) float f32x4;
typedef __attribute__((ext_vector_type(8))) short s16x8;

#define MTOTW 65792   // 257*256: fp32 W stride per a-index

__device__ __forceinline__ short f2bf(float f) {
    unsigned u = __builtin_bit_cast(unsigned, f);
    u = (u + 0x7fffu + ((u >> 16) & 1u)) >> 16;   // RNE
    return (short)u;
}

// async global->LDS, 16B per lane: LDS dest = uniform base + lane*16 (m97/m104)
__device__ __forceinline__ void gl16(const void* g, void* l) {
    __builtin_amdgcn_global_load_lds(
        (const __attribute__((address_space(1))) unsigned int*)g,
        (__attribute__((address_space(3))) unsigned int*)l, 16, 0, 0);
}

// ---- BK=64 swizzled tiles -----------------------------------------------
// Tile = [rows][64 shorts] (128 B/row = 8 x 16B chunks). gl16 dest linear;
// global source chunk is XORed by row&7; reads XOR the same way (involution,
// rule #21). Lanes of a b128 fragment read spread across all 8 slots.

// ---------- prep: l1,l2 -> bf16 (flat) ----------
__global__ __launch_bounds__(256) void conv_bf16(
    const float* __restrict__ a, const float* __restrict__ b,
    short* __restrict__ ao, short* __restrict__ bo)
{
    int i = blockIdx.x * 256 + threadIdx.x;
    const int HALF = 131072;
    float4 v; short* dst;
    if (i < HALF) { v = ((const float4*)a)[i]; dst = ao + (size_t)i * 4; }
    else          { v = ((const float4*)b)[i - HALF]; dst = bo + (size_t)(i - HALF) * 4; }
    short4 o; o.x = f2bf(v.x); o.y = f2bf(v.y); o.z = f2bf(v.z); o.w = f2bf(v.w);
    *(short4*)dst = o;
}

// ---------- prep: W3t[d][c] = bf16(W3[c][d]) ----------
__global__ __launch_bounds__(256) void prep_w3t(
    const float* __restrict__ W3, short* __restrict__ W3t)
{
    __shared__ float ld[32][33];
    int t = threadIdx.x, bx = blockIdx.x;
    int c0 = (bx >> 3) * 32, d0 = (bx & 7) * 32;
    int cr = t >> 3, dq = t & 7;
    float4 v = *(const float4*)&W3[(size_t)(c0 + cr) * 256 + d0 + dq * 4];
    ld[cr][dq*4+0] = v.x; ld[cr][dq*4+1] = v.y; ld[cr][dq*4+2] = v.z; ld[cr][dq*4+3] = v.w;
    __syncthreads();
    int dr = t >> 3, cq = t & 7;
    short4 o;
    o.x = f2bf(ld[cq*4+0][dr]); o.y = f2bf(ld[cq*4+1][dr]);
    o.z = f2bf(ld[cq*4+2][dr]); o.w = f2bf(ld[cq*4+3][dr]);
    *(short4*)&W3t[(size_t)(d0 + dr) * 256 + c0 + cq * 4] = o;
}

// ---------- prep: Wtp[c][a] = bf16(W[a][256][c]) (the b=256 plane, transposed) ----------
__global__ __launch_bounds__(256) void prep_wtail(
    const float* __restrict__ W1, const float* __restrict__ W2,
    short* __restrict__ Wtp1, short* __restrict__ Wtp2)
{
    __shared__ float ld[32][33];
    int t = threadIdx.x, bx = blockIdx.x;
    const float* W = blockIdx.y ? W2 : W1;
    short* Wtp = blockIdx.y ? Wtp2 : Wtp1;
    int a0 = (bx >> 3) * 32, c0 = (bx & 7) * 32;
    int ar = t >> 3, cq = t & 7;
    float4 v = *(const float4*)&W[(size_t)(a0 + ar) * MTOTW + 65536 + c0 + cq * 4];
    ld[ar][cq*4+0] = v.x; ld[ar][cq*4+1] = v.y; ld[ar][cq*4+2] = v.z; ld[ar][cq*4+3] = v.w;
    __syncthreads();
    int cr = t >> 3, aq = t & 7;
    short4 o;
    o.x = f2bf(ld[aq*4+0][cr]); o.y = f2bf(ld[aq*4+1][cr]);
    o.z = f2bf(ld[aq*4+2][cr]); o.w = f2bf(ld[aq*4+3][cr]);
    *(short4*)&Wtp[(size_t)(c0 + cr) * 256 + a0 + aq * 4] = o;
}

// ---------- prep: Wp[c][b][a] = bf16(W[a][b][c]) ----------
__global__ __launch_bounds__(256) void prep_wp(
    const float* __restrict__ W1, const float* __restrict__ W2,
    short* __restrict__ Wp1, short* __restrict__ Wp2)
{
    __shared__ float ld[32][33];
    int t = threadIdx.x, bx = blockIdx.x;
    int b = blockIdx.y;
    const float* W = blockIdx.z ? W2 : W1;
    short* Wp = blockIdx.z ? Wp2 : Wp1;
    int a0 = (bx >> 3) * 32, c0 = (bx & 7) * 32;
    int ar = t >> 3, cq = t & 7;
    float4 v = *(const float4*)&W[(size_t)(a0 + ar) * MTOTW + (size_t)b * 256 + c0 + cq * 4];
    ld[ar][cq*4+0] = v.x; ld[ar][cq*4+1] = v.y; ld[ar][cq*4+2] = v.z; ld[ar][cq*4+3] = v.w;
    __syncthreads();
    int cr = t >> 3, aq = t & 7;
    short4 o;
    o.x = f2bf(ld[aq*4+0][cr]); o.y = f2bf(ld[aq*4+1][cr]);
    o.z = f2bf(ld[aq*4+2][cr]); o.w = f2bf(ld[aq*4+3][cr]);
    *(short4*)&Wp[((size_t)(c0 + cr) * 256 + b) * 256 + a0 + aq * 4] = o;
}

// ---------- tail_mfma: unchanged (small, one-shot) ----------
__global__ __launch_bounds__(256, 2) void tail_mfma(
    const short* __restrict__ l1b,
    const short* __restrict__ Wtp1, const short* __restrict__ Wtp2,
    const float* __restrict__ W1, const float* __restrict__ W2,
    float* __restrict__ tail1, float* __restrict__ tail2)
{
    __shared__ __align__(16) short Al[128 * 32];
    __shared__ __align__(16) short Bl[128 * 32];
    int t = threadIdx.x, w = t >> 6, lane = t & 63;
    int l4 = lane >> 2, kq = lane & 3;
    int rt = blockIdx.x, nt = blockIdx.y, ten = blockIdx.z;
    const short* Wtp = ten ? Wtp2 : Wtp1;
    const float* Wf = ten ? W2 : W1;
    float* tail = ten ? tail2 : tail1;
    const short* Ab = l1b + (size_t)(rt * 128) * 256;
    const short* Bb = Wtp + (size_t)(nt * 128) * 256;

    f32x4 acc[4][4] = {};
    int m0w = (w >> 1) * 64, n0w = (w & 1) * 64;

    for (int k0 = 0; k0 < 256; k0 += 32) {
        __syncthreads();
        #pragma unroll
        for (int q = 0; q < 4; ++q) {
            int seg = w * 4 + q;
            if (seg < 8)
                gl16(Ab + (size_t)(seg * 16 + l4) * 256 + k0 + kq * 8, &Al[seg * 512]);
            else
                gl16(Bb + (size_t)((seg - 8) * 16 + l4) * 256 + k0 + kq * 8, &Bl[(seg - 8) * 512]);
        }
        __syncthreads();
        s16x8 af[4], bf[4];
        #pragma unroll
        for (int i = 0; i < 4; ++i) {
            af[i] = *(const s16x8*)&Al[(m0w + i * 16 + (lane & 15)) * 32 + (lane >> 4) * 8];
            bf[i] = *(const s16x8*)&Bl[(n0w + i * 16 + (lane & 15)) * 32 + (lane >> 4) * 8];
        }
        #pragma unroll
        for (int mi = 0; mi < 4; ++mi)
            #pragma unroll
            for (int ni = 0; ni < 4; ++ni)
                acc[mi][ni] = __builtin_amdgcn_mfma_f32_16x16x32_bf16(af[mi], bf[ni], acc[mi][ni], 0, 0, 0);
    }
    #pragma unroll
    for (int ni = 0; ni < 4; ++ni) {
        int c = nt * 128 + n0w + ni * 16 + (lane & 15);
        float tl = Wf[(size_t)256 * MTOTW + 65536 + c];   // a=256,b=256 term (coeff 1)
        #pragma unroll
        for (int mi = 0; mi < 4; ++mi) {
            int r = rt * 128 + m0w + mi * 16 + (lane >> 4) * 4;
            #pragma unroll
            for (int reg = 0; reg < 4; ++reg)
                tail[(size_t)(r + reg) * 256 + c] = acc[mi][ni][reg] + tl;
        }
    }
}

// ---------- stage1: T[rl][c][b] = bf16( sum_a l1b[r][a]*Wp[c][b][a] + W[256][b][c] ) ----------
// BK=64 swizzled tiles (R7). Changes this round:
// (1) launch_bounds (256,4): demand ~64 AGPR + ~47 VGPR = 111 <= 128 cap; R4's
//     run of this config showed no spill and ~52us. LDS 32KB x4 = 128KB OK.
// (2) panel-grouped XCD swizzle: the 2*gdx sibling blocks sharing one Wp panel
//     (all rt x bt of one zc) are CONTIGUOUS in swz -> same XCD -> panel read
//     once into that XCD's L2 (16 concurrent panels x 128KB = 2MB <= 4MB L2)
//     instead of 8x from L3.
__global__ __launch_bounds__(256, 4) void stage1(
    const short* __restrict__ l1b,
    const short* __restrict__ Wp1, const short* __restrict__ Wp2,
    const float* __restrict__ W1, const float* __restrict__ W2,
    short* __restrict__ T1, short* __restrict__ T2, int row0)
{
    __shared__ __align__(16) short S[16384];
    int t = threadIdx.x, w = t >> 6, lane = t & 63;
    int srow8 = lane >> 3;                       // row-within-seg (0..7)
    int sch   = (lane & 7) ^ srow8;              // swizzled source chunk
    int fr    = lane & 15, fb7 = lane & 7;

    // --- XCD swizzle: contiguous swz per XCD, siblings-first decode ---
    unsigned gdx = gridDim.x;                    // power of 2 (chunk/128)
    unsigned orig = blockIdx.x + gdx * (blockIdx.y + 2u * blockIdx.z);
    unsigned nwg = gdx * 1024u;
    unsigned swz = (orig & 7u) * (nwg >> 3) + (orig >> 3);
    unsigned sg  = 2u * gdx;                     // siblings per panel
    unsigned sib = swz % sg;
    unsigned pg  = swz / sg;                     // panel id = zc, [0,512)
    int rt = sib & (gdx - 1u);
    int bt = sib / gdx;
    int zc = pg;

    int c = zc >> 1, ten = zc & 1;
    const short* Wp = ten ? Wp2 : Wp1;
    const float* Wf = ten ? W2 : W1;
    short* T = ten ? T2 : T1;
    int r0g = row0 + rt * 128;
    int b0 = bt * 128;
    const short* Ab = l1b + (size_t)r0g * 256;
    const short* Bb = Wp + ((size_t)c * 256 + b0) * 256;

    f32x4 acc[4][4] = {};
    int m0w = (w >> 1) * 64, n0w = (w & 1) * 64;

    for (int kt = 0; kt < 4; ++kt) {
        int k0 = kt * 64;
        __syncthreads();
        #pragma unroll
        for (int q = 0; q < 8; ++q) {            // 16 A segs + 16 B segs, 8/wave
            int seg = w * 8 + q;
            int rloc = (seg & 15) * 8 + srow8;   // tile row 0..127
            const short* gb = (seg < 16) ? Ab : Bb;
            gl16(gb + (size_t)rloc * 256 + k0 + sch * 8, &S[seg * 512]);
        }
        __syncthreads();
        #pragma unroll
        for (int ss = 0; ss < 2; ++ss) {
            int cx = ((ss * 4 + (lane >> 4)) ^ fb7) * 8;
            s16x8 af[4], bf[4];
            #pragma unroll
            for (int i = 0; i < 4; ++i) {
                af[i] = *(const s16x8*)&S[(m0w + i * 16 + fr) * 64 + cx];
                bf[i] = *(const s16x8*)&S[8192 + (n0w + i * 16 + fr) * 64 + cx];
            }
            #pragma unroll
            for (int mi = 0; mi < 4; ++mi)
                #pragma unroll
                for (int ni = 0; ni < 4; ++ni)
                    acc[mi][ni] = __builtin_amdgcn_mfma_f32_16x16x32_bf16(af[mi], bf[ni], acc[mi][ni], 0, 0, 0);
        }
    }
    __syncthreads();   // all waves done reading staging before Cep overlays it

    // epilogue: repack wave's 64x64 through LDS (per-wave region, no further sync)
    short* Cw = &S[w * 4096];
    #pragma unroll
    for (int ni = 0; ni < 4; ++ni) {
        int b = b0 + n0w + ni * 16 + (lane & 15);
        float tl = Wf[(size_t)256 * MTOTW + (size_t)b * 256 + c];   // a=256 tail, fp32
        #pragma unroll
        for (int mi = 0; mi < 4; ++mi)
            #pragma unroll
            for (int reg = 0; reg < 4; ++reg) {
                int lr = mi * 16 + (lane >> 4) * 4 + reg;           // wave-local row
                int lc = ni * 16 + (lane & 15);                     // wave-local col
                Cw[lr * 64 + lc] = f2bf(acc[mi][ni][reg] + tl);
            }
    }
    #pragma unroll
    for (int s = 0; s < 8; ++s) {
        int row = s * 8 + (lane >> 3);
        int co = (lane & 7) * 8;
        int rl = rt * 128 + m0w + row;                              // chunk-local row
        int gb = b0 + n0w + co;
        *(int4*)&T[((size_t)rl * 256 + c) * 256 + gb] = *(int4*)&Cw[row * 64 + co];
    }
}

// ---------- stage2: FROZEN at R7 (control: 81us, MfmaUtil 26) ----------
__global__ __launch_bounds__(256, 2) void stage2(
    const short* __restrict__ l2b,
    const short* __restrict__ T1, const short* __restrict__ T2,
    const float* __restrict__ tail1, const float* __restrict__ tail2,
    const float* __restrict__ h1, const float* __restrict__ h2,
    const short* __restrict__ W3t, float* __restrict__ out, int row0)
{
    __shared__ __align__(16) short S2[36864];   // 72 KB
    int t = threadIdx.x, w = t >> 6, lane = t & 63;
    int srow8 = lane >> 3;
    int sch   = (lane & 7) ^ srow8;
    int fr    = lane & 15, fb7 = lane & 7;

    // --- bijective XCD-aware swizzle (nwg = 4*chunk, chunk pow2 -> %8==0) ---
    unsigned orig = blockIdx.x + (blockIdx.y << 2);
    unsigned nwg = gridDim.y << 2;
    unsigned swz = (orig & 7u) * (nwg >> 3) + (orig >> 3);
    int jt = swz & 3, rl = swz >> 2;

    int rg = row0 + rl, n = rg >> 8, j0 = jt * 64;
    const short* Arow = l2b + ((size_t)n * 256 + j0) * 256;
    const short* Tt1 = T1 + (size_t)rl * 65536;
    const short* Tt2 = T2 + (size_t)rl * 65536;
    int n0w = w * 64;

    // ---- phase A: U1 and U2 together (A shared), BK=64 ----
    f32x4 acc1[4][4] = {}, acc2[4][4] = {};
    for (int kt = 0; kt < 4; ++kt) {
        int k0 = kt * 64;
        __syncthreads();
        #pragma unroll
        for (int q = 0; q < 18; ++q) {           // 8 Al + 32 B1 + 32 B2 = 72 segs
            int seg = w * 18 + q;
            const short* gb; short* lb; int rloc;
            if (seg < 8)       { rloc = seg * 8 + srow8;        gb = Arow; lb = &S2[seg * 512]; }
            else if (seg < 40) { rloc = (seg - 8) * 8 + srow8;  gb = Tt1;  lb = &S2[4096 + (seg - 8) * 512]; }
            else               { rloc = (seg - 40) * 8 + srow8; gb = Tt2;  lb = &S2[20480 + (seg - 40) * 512]; }
            gl16(gb + (size_t)rloc * 256 + k0 + sch * 8, lb);
        }
        __syncthreads();
        #pragma unroll
        for (int ss = 0; ss < 2; ++ss) {
            int cx = ((ss * 4 + (lane >> 4)) ^ fb7) * 8;
            s16x8 af[4], b1[4], b2[4];
            #pragma unroll
            for (int i = 0; i < 4; ++i) {
                af[i] = *(const s16x8*)&S2[(i * 16 + fr) * 64 + cx];
                b1[i] = *(const s16x8*)&S2[4096 + (n0w + i * 16 + fr) * 64 + cx];
                b2[i] = *(const s16x8*)&S2[20480 + (n0w + i * 16 + fr) * 64 + cx];
            }
            #pragma unroll
            for (int mi = 0; mi < 4; ++mi)
                #pragma unroll
                for (int ni = 0; ni < 4; ++ni) {
                    acc1[mi][ni] = __builtin_amdgcn_mfma_f32_16x16x32_bf16(af[mi], b1[ni], acc1[mi][ni], 0, 0, 0);
                    acc2[mi][ni] = __builtin_amdgcn_mfma_f32_16x16x32_bf16(af[mi], b2[ni], acc2[mi][ni], 0, 0, 0);
                }
        }
    }
    __syncthreads();   // staging reads complete before V1 overlays

    // V1 = h1*(U1+tail1) -> LDS bf16 ; v2 = h2*(U2+tail2) -> regs
    short* V1 = S2;                              // [64][264], overlays Al/B1l
    f32x4 v2[4][4];
    #pragma unroll
    for (int ni = 0; ni < 4; ++ni) {
        int c = n0w + ni * 16 + (lane & 15);
        float hh1 = h1[(size_t)rg * 256 + c], tl1 = tail1[(size_t)rg * 256 + c];
        float hh2 = h2[(size_t)rg * 256 + c], tl2 = tail2[(size_t)rg * 256 + c];
        #pragma unroll
        for (int mi = 0; mi < 4; ++mi)
            #pragma unroll
            for (int reg = 0; reg < 4; ++reg) {
                int j = mi * 16 + (lane >> 4) * 4 + reg;
                V1[j * 264 + c] = f2bf(hh1 * (acc1[mi][ni][reg] + tl1));
                v2[mi][ni][reg] = hh2 * (acc2[mi][ni][reg] + tl2);
            }
    }
    __syncthreads();   // V1 visible

    // ---- phase B: P = V1 @ W3t^T, BK=64 (W3t tile at [20480,36864), swizzled) ----
    f32x4 accP[4][4] = {};
    for (int kt = 0; kt < 4; ++kt) {
        int k0 = kt * 64;
        __syncthreads();
        #pragma unroll
        for (int q = 0; q < 8; ++q) {            // 32 segs of W3t 256x64
            int seg = w * 8 + q;
            int rloc = seg * 8 + srow8;
            gl16(W3t + (size_t)rloc * 256 + k0 + sch * 8, &S2[20480 + seg * 512]);
        }
        __syncthreads();
        #pragma unroll
        for (int ss = 0; ss < 2; ++ss) {
            int cx = ((ss * 4 + (lane >> 4)) ^ fb7) * 8;
            s16x8 af[4], bf[4];
            #pragma unroll
            for (int i = 0; i < 4; ++i) {
                af[i] = *(const s16x8*)&V1[(i * 16 + fr) * 264 + k0 + ss * 32 + (lane >> 4) * 8];
                bf[i] = *(const s16x8*)&S2[20480 + (n0w + i * 16 + fr) * 64 + cx];
            }
            #pragma unroll
            for (int mi = 0; mi < 4; ++mi)
                #pragma unroll
                for (int ni = 0; ni < 4; ++ni)
                    accP[mi][ni] = __builtin_amdgcn_mfma_f32_16x16x32_bf16(af[mi], bf[ni], accP[mi][ni], 0, 0, 0);
        }
    }

    // out[j] = sum_d P[j][d] * V2[j][d]
    float* part = (float*)&S2[16896];            // disjoint from V1 and W3t tile
    #pragma unroll
    for (int mi = 0; mi < 4; ++mi)
        #pragma unroll
        for (int reg = 0; reg < 4; ++reg) {
            float s = 0.f;
            #pragma unroll
            for (int ni = 0; ni < 4; ++ni) s += accP[mi][ni][reg] * v2[mi][ni][reg];
            s += __shfl_xor(s, 1); s += __shfl_xor(s, 2);
            s += __shfl_xor(s, 4); s += __shfl_xor(s, 8);
            if ((lane & 15) == 0)
                part[(mi * 16 + (lane >> 4) * 4 + reg) * 4 + w] = s;
        }
    __syncthreads();
    if (t < 64)
        out[(size_t)rg * 256 + j0 + t] = part[t*4] + part[t*4+1] + part[t*4+2] + part[t*4+3];
}

extern "C" void kernel_launch(void* const* d_in, const int* in_sizes, int n_in,
                              void* d_out, int out_size, void* d_ws, size_t ws_size,
                              hipStream_t stream) {
    const float* layer1 = (const float*)d_in[0];
    const float* layer2 = (const float*)d_in[1];
    const float* h1     = (const float*)d_in[2];
    const float* h2     = (const float*)d_in[3];
    const float* W1     = (const float*)d_in[4];
    const float* W2     = (const float*)d_in[5];
    const float* W3     = (const float*)d_in[6];
    float* out = (float*)d_out;

    short* Wp1  = (short*)d_ws;                  // 33.55 MB
    short* Wp2  = Wp1 + 16777216;
    short* l1b  = Wp2 + 16777216;                // 2048x256
    short* l2b  = l1b + 524288;
    short* W3t  = l2b + 524288;                  // 256x256
    short* Wtp1 = W3t + 65536;                   // 256x256
    short* Wtp2 = Wtp1 + 65536;
    float* tail1 = (float*)(Wtp2 + 65536);       // 2048x256 fp32
    float* tail2 = tail1 + 524288;
    short* T1   = (short*)(tail2 + 524288);
    const size_t head = (size_t)(16777216*2 + 524288*2 + 65536*3) * 2 + (size_t)524288 * 2 * 4;
    int chunk = 2048;
    while (head + (size_t)chunk * 262144 > ws_size && chunk > 128) chunk >>= 1;
    short* T2 = T1 + (size_t)chunk * 65536;

    conv_bf16<<<1024, 256, 0, stream>>>(layer1, layer2, l1b, l2b);
    prep_w3t<<<64, 256, 0, stream>>>(W3, W3t);
    prep_wtail<<<dim3(64, 2), 256, 0, stream>>>(W1, W2, Wtp1, Wtp2);
    prep_wp<<<dim3(64, 256, 2), 256, 0, stream>>>(W1, W2, Wp1, Wp2);
    tail_mfma<<<dim3(16, 2, 2), 256, 0, stream>>>(l1b, Wtp1, Wtp2, W1, W2, tail1, tail2);

    for (int row0 = 0; row0 < 2048; row0 += chunk) {
        stage1<<<dim3(chunk / 128, 2, 512), 256, 0, stream>>>(
            l1b, Wp1, Wp2, W1, W2, T1, T2, row0);
        stage2<<<dim3(4, chunk), 256, 0, stream>>>(
            l2b, T1, T2, tail1, tail2, h1, h2, W3t, out, row0);
    }
}

// Round 10
// 644.054 us; speedup vs baseline: 2.6409x; 1.0560x over previous
//
#include <hip/hip_runtime.h>

typedef __attribute__((ext_vector_type(4))) float f32x4;
typedef __attribute__((ext_vector_type(8))) short s16x8;

#define MTOTW 65792   // 257*256: fp32 W stride per a-index

__device__ __forceinline__ short f2bf(float f) {
    unsigned u = __builtin_bit_cast(unsigned, f);
    u = (u + 0x7fffu + ((u >> 16) & 1u)) >> 16;   // RNE
    return (short)u;
}

// async global->LDS, 16B per lane: LDS dest = uniform base + lane*16 (m97/m104)
__device__ __forceinline__ void gl16(const void* g, void* l) {
    __builtin_amdgcn_global_load_lds(
        (const __attribute__((address_space(1))) unsigned int*)g,
        (__attribute__((address_space(3))) unsigned int*)l, 16, 0, 0);
}

// ---- BK=64 swizzled tiles -----------------------------------------------
// Tile = [rows][64 shorts] (128 B/row = 8 x 16B chunks). gl16 dest linear;
// global source chunk is XORed by row&7; reads XOR the same way (involution,
// rule #21). Lanes of a b128 fragment read spread across all 8 slots.

// ---------- prep: l1,l2 -> bf16 (flat) ----------
__global__ __launch_bounds__(256) void conv_bf16(
    const float* __restrict__ a, const float* __restrict__ b,
    short* __restrict__ ao, short* __restrict__ bo)
{
    int i = blockIdx.x * 256 + threadIdx.x;
    const int HALF = 131072;
    float4 v; short* dst;
    if (i < HALF) { v = ((const float4*)a)[i]; dst = ao + (size_t)i * 4; }
    else          { v = ((const float4*)b)[i - HALF]; dst = bo + (size_t)(i - HALF) * 4; }
    short4 o; o.x = f2bf(v.x); o.y = f2bf(v.y); o.z = f2bf(v.z); o.w = f2bf(v.w);
    *(short4*)dst = o;
}

// ---------- prep: W3t[d][c] = bf16(W3[c][d]) ----------
__global__ __launch_bounds__(256) void prep_w3t(
    const float* __restrict__ W3, short* __restrict__ W3t)
{
    __shared__ float ld[32][33];
    int t = threadIdx.x, bx = blockIdx.x;
    int c0 = (bx >> 3) * 32, d0 = (bx & 7) * 32;
    int cr = t >> 3, dq = t & 7;
    float4 v = *(const float4*)&W3[(size_t)(c0 + cr) * 256 + d0 + dq * 4];
    ld[cr][dq*4+0] = v.x; ld[cr][dq*4+1] = v.y; ld[cr][dq*4+2] = v.z; ld[cr][dq*4+3] = v.w;
    __syncthreads();
    int dr = t >> 3, cq = t & 7;
    short4 o;
    o.x = f2bf(ld[cq*4+0][dr]); o.y = f2bf(ld[cq*4+1][dr]);
    o.z = f2bf(ld[cq*4+2][dr]); o.w = f2bf(ld[cq*4+3][dr]);
    *(short4*)&W3t[(size_t)(d0 + dr) * 256 + c0 + cq * 4] = o;
}

// ---------- prep: Wtp[c][a] = bf16(W[a][256][c]) (the b=256 plane, transposed) ----------
__global__ __launch_bounds__(256) void prep_wtail(
    const float* __restrict__ W1, const float* __restrict__ W2,
    short* __restrict__ Wtp1, short* __restrict__ Wtp2)
{
    __shared__ float ld[32][33];
    int t = threadIdx.x, bx = blockIdx.x;
    const float* W = blockIdx.y ? W2 : W1;
    short* Wtp = blockIdx.y ? Wtp2 : Wtp1;
    int a0 = (bx >> 3) * 32, c0 = (bx & 7) * 32;
    int ar = t >> 3, cq = t & 7;
    float4 v = *(const float4*)&W[(size_t)(a0 + ar) * MTOTW + 65536 + c0 + cq * 4];
    ld[ar][cq*4+0] = v.x; ld[ar][cq*4+1] = v.y; ld[ar][cq*4+2] = v.z; ld[ar][cq*4+3] = v.w;
    __syncthreads();
    int cr = t >> 3, aq = t & 7;
    short4 o;
    o.x = f2bf(ld[aq*4+0][cr]); o.y = f2bf(ld[aq*4+1][cr]);
    o.z = f2bf(ld[aq*4+2][cr]); o.w = f2bf(ld[aq*4+3][cr]);
    *(short4*)&Wtp[(size_t)(c0 + cr) * 256 + a0 + aq * 4] = o;
}

// ---------- prep: Wp[c][b][a] = bf16(W[a][b][c]) ----------
__global__ __launch_bounds__(256) void prep_wp(
    const float* __restrict__ W1, const float* __restrict__ W2,
    short* __restrict__ Wp1, short* __restrict__ Wp2)
{
    __shared__ float ld[32][33];
    int t = threadIdx.x, bx = blockIdx.x;
    int b = blockIdx.y;
    const float* W = blockIdx.z ? W2 : W1;
    short* Wp = blockIdx.z ? Wp2 : Wp1;
    int a0 = (bx >> 3) * 32, c0 = (bx & 7) * 32;
    int ar = t >> 3, cq = t & 7;
    float4 v = *(const float4*)&W[(size_t)(a0 + ar) * MTOTW + (size_t)b * 256 + c0 + cq * 4];
    ld[ar][cq*4+0] = v.x; ld[ar][cq*4+1] = v.y; ld[ar][cq*4+2] = v.z; ld[ar][cq*4+3] = v.w;
    __syncthreads();
    int cr = t >> 3, aq = t & 7;
    short4 o;
    o.x = f2bf(ld[aq*4+0][cr]); o.y = f2bf(ld[aq*4+1][cr]);
    o.z = f2bf(ld[aq*4+2][cr]); o.w = f2bf(ld[aq*4+3][cr]);
    *(short4*)&Wp[((size_t)(c0 + cr) * 256 + b) * 256 + a0 + aq * 4] = o;
}

// ---------- tail_mfma: unchanged (small, one-shot) ----------
__global__ __launch_bounds__(256, 2) void tail_mfma(
    const short* __restrict__ l1b,
    const short* __restrict__ Wtp1, const short* __restrict__ Wtp2,
    const float* __restrict__ W1, const float* __restrict__ W2,
    float* __restrict__ tail1, float* __restrict__ tail2)
{
    __shared__ __align__(16) short Al[128 * 32];
    __shared__ __align__(16) short Bl[128 * 32];
    int t = threadIdx.x, w = t >> 6, lane = t & 63;
    int l4 = lane >> 2, kq = lane & 3;
    int rt = blockIdx.x, nt = blockIdx.y, ten = blockIdx.z;
    const short* Wtp = ten ? Wtp2 : Wtp1;
    const float* Wf = ten ? W2 : W1;
    float* tail = ten ? tail2 : tail1;
    const short* Ab = l1b + (size_t)(rt * 128) * 256;
    const short* Bb = Wtp + (size_t)(nt * 128) * 256;

    f32x4 acc[4][4] = {};
    int m0w = (w >> 1) * 64, n0w = (w & 1) * 64;

    for (int k0 = 0; k0 < 256; k0 += 32) {
        __syncthreads();
        #pragma unroll
        for (int q = 0; q < 4; ++q) {
            int seg = w * 4 + q;
            if (seg < 8)
                gl16(Ab + (size_t)(seg * 16 + l4) * 256 + k0 + kq * 8, &Al[seg * 512]);
            else
                gl16(Bb + (size_t)((seg - 8) * 16 + l4) * 256 + k0 + kq * 8, &Bl[(seg - 8) * 512]);
        }
        __syncthreads();
        s16x8 af[4], bf[4];
        #pragma unroll
        for (int i = 0; i < 4; ++i) {
            af[i] = *(const s16x8*)&Al[(m0w + i * 16 + (lane & 15)) * 32 + (lane >> 4) * 8];
            bf[i] = *(const s16x8*)&Bl[(n0w + i * 16 + (lane & 15)) * 32 + (lane >> 4) * 8];
        }
        #pragma unroll
        for (int mi = 0; mi < 4; ++mi)
            #pragma unroll
            for (int ni = 0; ni < 4; ++ni)
                acc[mi][ni] = __builtin_amdgcn_mfma_f32_16x16x32_bf16(af[mi], bf[ni], acc[mi][ni], 0, 0, 0);
    }
    #pragma unroll
    for (int ni = 0; ni < 4; ++ni) {
        int c = nt * 128 + n0w + ni * 16 + (lane & 15);
        float tl = Wf[(size_t)256 * MTOTW + 65536 + c];   // a=256,b=256 term (coeff 1)
        #pragma unroll
        for (int mi = 0; mi < 4; ++mi) {
            int r = rt * 128 + m0w + mi * 16 + (lane >> 4) * 4;
            #pragma unroll
            for (int reg = 0; reg < 4; ++reg)
                tail[(size_t)(r + reg) * 256 + c] = acc[mi][ni][reg] + tl;
        }
    }
}

// ---------- stage1: FROZEN at R8 (BK=64 swizzle, (256,4), panel-grouped XCD) ----------
__global__ __launch_bounds__(256, 4) void stage1(
    const short* __restrict__ l1b,
    const short* __restrict__ Wp1, const short* __restrict__ Wp2,
    const float* __restrict__ W1, const float* __restrict__ W2,
    short* __restrict__ T1, short* __restrict__ T2, int row0)
{
    __shared__ __align__(16) short S[16384];
    int t = threadIdx.x, w = t >> 6, lane = t & 63;
    int srow8 = lane >> 3;                       // row-within-seg (0..7)
    int sch   = (lane & 7) ^ srow8;              // swizzled source chunk
    int fr    = lane & 15, fb7 = lane & 7;

    // --- XCD swizzle: contiguous swz per XCD, siblings-first decode ---
    unsigned gdx = gridDim.x;                    // power of 2 (chunk/128)
    unsigned orig = blockIdx.x + gdx * (blockIdx.y + 2u * blockIdx.z);
    unsigned nwg = gdx * 1024u;
    unsigned swz = (orig & 7u) * (nwg >> 3) + (orig >> 3);
    unsigned sg  = 2u * gdx;                     // siblings per panel
    unsigned sib = swz % sg;
    unsigned pg  = swz / sg;                     // panel id = zc, [0,512)
    int rt = sib & (gdx - 1u);
    int bt = sib / gdx;
    int zc = pg;

    int c = zc >> 1, ten = zc & 1;
    const short* Wp = ten ? Wp2 : Wp1;
    const float* Wf = ten ? W2 : W1;
    short* T = ten ? T2 : T1;
    int r0g = row0 + rt * 128;
    int b0 = bt * 128;
    const short* Ab = l1b + (size_t)r0g * 256;
    const short* Bb = Wp + ((size_t)c * 256 + b0) * 256;

    f32x4 acc[4][4] = {};
    int m0w = (w >> 1) * 64, n0w = (w & 1) * 64;

    for (int kt = 0; kt < 4; ++kt) {
        int k0 = kt * 64;
        __syncthreads();
        #pragma unroll
        for (int q = 0; q < 8; ++q) {            // 16 A segs + 16 B segs, 8/wave
            int seg = w * 8 + q;
            int rloc = (seg & 15) * 8 + srow8;   // tile row 0..127
            const short* gb = (seg < 16) ? Ab : Bb;
            gl16(gb + (size_t)rloc * 256 + k0 + sch * 8, &S[seg * 512]);
        }
        __syncthreads();
        #pragma unroll
        for (int ss = 0; ss < 2; ++ss) {
            int cx = ((ss * 4 + (lane >> 4)) ^ fb7) * 8;
            s16x8 af[4], bf[4];
            #pragma unroll
            for (int i = 0; i < 4; ++i) {
                af[i] = *(const s16x8*)&S[(m0w + i * 16 + fr) * 64 + cx];
                bf[i] = *(const s16x8*)&S[8192 + (n0w + i * 16 + fr) * 64 + cx];
            }
            #pragma unroll
            for (int mi = 0; mi < 4; ++mi)
                #pragma unroll
                for (int ni = 0; ni < 4; ++ni)
                    acc[mi][ni] = __builtin_amdgcn_mfma_f32_16x16x32_bf16(af[mi], bf[ni], acc[mi][ni], 0, 0, 0);
        }
    }
    __syncthreads();   // all waves done reading staging before Cep overlays it

    // epilogue: repack wave's 64x64 through LDS (per-wave region, no further sync)
    short* Cw = &S[w * 4096];
    #pragma unroll
    for (int ni = 0; ni < 4; ++ni) {
        int b = b0 + n0w + ni * 16 + (lane & 15);
        float tl = Wf[(size_t)256 * MTOTW + (size_t)b * 256 + c];   // a=256 tail, fp32
        #pragma unroll
        for (int mi = 0; mi < 4; ++mi)
            #pragma unroll
            for (int reg = 0; reg < 4; ++reg) {
                int lr = mi * 16 + (lane >> 4) * 4 + reg;           // wave-local row
                int lc = ni * 16 + (lane & 15);                     // wave-local col
                Cw[lr * 64 + lc] = f2bf(acc[mi][ni][reg] + tl);
            }
    }
    #pragma unroll
    for (int s = 0; s < 8; ++s) {
        int row = s * 8 + (lane >> 3);
        int co = (lane & 7) * 8;
        int rl = rt * 128 + m0w + row;                              // chunk-local row
        int gb = b0 + n0w + co;
        *(int4*)&T[((size_t)rl * 256 + c) * 256 + gb] = *(int4*)&Cw[row * 64 + co];
    }
}

// ---------- stage2: phase A = counted-vmcnt dbuf (FENCED), phase B = R8 serial ----------
// R9's race fix: every raw s_barrier is pinned with sched_barrier(0) on both
// sides (rule #18 / m201 discipline) so ds_reads cannot hoist above the
// leading barrier and next-tile gl16 writes cannot hoist above the trailing
// one. Phase A split into two half-phases (acc1 over T1, acc2 over T2):
// per-K-step staging 40 KB -> dbuf fits 80 KB (2 blocks/CU unchanged).
// Schedule/K-step: issue stage(kt+1) -> vmcnt(10) (kt+1's 10 loads stay in
// flight) -> s_barrier -> ds_read+MFMA(kt) -> s_barrier. vmcnt(0) only at the
// last step. Phase B: R8-proven serial __syncthreads loop, BK=64.
// LDS (shorts): phA buf0 [0,20480) {Al 4096|B 16384}, buf1 [20480,40960).
// Post-A overlay: V1 [0,16896) | part [16896,17408) | W3t tile [17408,33792).
__global__ __launch_bounds__(256, 2) void stage2(
    const short* __restrict__ l2b,
    const short* __restrict__ T1, const short* __restrict__ T2,
    const float* __restrict__ tail1, const float* __restrict__ tail2,
    const float* __restrict__ h1, const float* __restrict__ h2,
    const short* __restrict__ W3t, float* __restrict__ out, int row0)
{
    __shared__ __align__(16) short S2[40960];   // 80 KB -> 2 blocks/CU
    int t = threadIdx.x, w = t >> 6, lane = t & 63;
    int srow8 = lane >> 3;
    int sch   = (lane & 7) ^ srow8;              // BK=64 swizzle (8 chunks)
    int fr    = lane & 15, fb7 = lane & 7;

    // --- bijective XCD-aware swizzle (nwg = 4*chunk, chunk pow2 -> %8==0) ---
    unsigned orig = blockIdx.x + (blockIdx.y << 2);
    unsigned nwg = gridDim.y << 2;
    unsigned swz = (orig & 7u) * (nwg >> 3) + (orig >> 3);
    int jt = swz & 3, rl = swz >> 2;

    int rg = row0 + rl, n = rg >> 8, j0 = jt * 64;
    const short* Arow = l2b + ((size_t)n * 256 + j0) * 256;
    const short* Tt1 = T1 + (size_t)rl * 65536;
    const short* Tt2 = T2 + (size_t)rl * 65536;
    int n0w = w * 64;

    f32x4 acc1[4][4] = {}, acc2[4][4] = {};

    // half-phase: acc = Arow x Tt^T over K=256, BK=64, dbuf, counted vmcnt
    auto half_phase = [&](const short* Tt, f32x4 (&acc)[4][4]) {
        #pragma unroll
        for (int q = 0; q < 10; ++q) {           // prologue: kt=0 -> buf0
            int seg = w * 10 + q;
            if (seg < 8) gl16(Arow + (size_t)(seg * 8 + srow8) * 256 + sch * 8, &S2[seg * 512]);
            else         gl16(Tt + (size_t)((seg - 8) * 8 + srow8) * 256 + sch * 8, &S2[4096 + (seg - 8) * 512]);
        }
        __builtin_amdgcn_sched_barrier(0);
        for (int kt = 0; kt < 4; ++kt) {
            int cur = (kt & 1) * 20480;
            if (kt < 3) {
                int nb = 20480 - cur, k0 = (kt + 1) * 64;
                #pragma unroll
                for (int q = 0; q < 10; ++q) {
                    int seg = w * 10 + q;
                    if (seg < 8) gl16(Arow + (size_t)(seg * 8 + srow8) * 256 + k0 + sch * 8, &S2[nb + seg * 512]);
                    else         gl16(Tt + (size_t)((seg - 8) * 8 + srow8) * 256 + k0 + sch * 8, &S2[nb + 4096 + (seg - 8) * 512]);
                }
                __builtin_amdgcn_sched_barrier(0);
                asm volatile("s_waitcnt vmcnt(10)" ::: "memory");   // kt's 10 done; kt+1's fly
            } else {
                asm volatile("s_waitcnt vmcnt(0)" ::: "memory");
            }
            __builtin_amdgcn_s_barrier();                // all waves staged tile kt
            __builtin_amdgcn_sched_barrier(0);           // ds_reads stay BELOW barrier
            #pragma unroll
            for (int ss = 0; ss < 2; ++ss) {
                int cx = ((ss * 4 + (lane >> 4)) ^ fb7) * 8;
                s16x8 af[4], bf[4];
                #pragma unroll
                for (int i = 0; i < 4; ++i) {
                    af[i] = *(const s16x8*)&S2[cur + (i * 16 + fr) * 64 + cx];
                    bf[i] = *(const s16x8*)&S2[cur + 4096 + (n0w + i * 16 + fr) * 64 + cx];
                }
                #pragma unroll
                for (int mi = 0; mi < 4; ++mi)
                    #pragma unroll
                    for (int ni = 0; ni < 4; ++ni)
                        acc[mi][ni] = __builtin_amdgcn_mfma_f32_16x16x32_bf16(af[mi], bf[ni], acc[mi][ni], 0, 0, 0);
            }
            __builtin_amdgcn_sched_barrier(0);           // reads/MFMA stay ABOVE barrier
            __builtin_amdgcn_s_barrier();                // reads done before next staging
            __builtin_amdgcn_sched_barrier(0);           // next gl16s stay BELOW barrier
        }
    };
    half_phase(Tt1, acc1);
    half_phase(Tt2, acc2);

    __syncthreads();   // phase boundary: full drain; overlay-safe

    short* V1 = S2;                              // [64][264] -> [0,16896)
    float* part = (float*)&S2[16896];            // [16896,17408)

    // V1 = h1*(U1+tail1) -> LDS bf16 ; v2 = h2*(U2+tail2) -> regs
    f32x4 v2[4][4];
    #pragma unroll
    for (int ni = 0; ni < 4; ++ni) {
        int c = n0w + ni * 16 + (lane & 15);
        float hh1 = h1[(size_t)rg * 256 + c], tl1 = tail1[(size_t)rg * 256 + c];
        float hh2 = h2[(size_t)rg * 256 + c], tl2 = tail2[(size_t)rg * 256 + c];
        #pragma unroll
        for (int mi = 0; mi < 4; ++mi)
            #pragma unroll
            for (int reg = 0; reg < 4; ++reg) {
                int j = mi * 16 + (lane >> 4) * 4 + reg;
                V1[j * 264 + c] = f2bf(hh1 * (acc1[mi][ni][reg] + tl1));
                v2[mi][ni][reg] = hh2 * (acc2[mi][ni][reg] + tl2);
            }
    }

    // ---- phase B: P = V1 @ W3t^T, BK=64, R8-style serial (W3t tile [17408,33792)) ----
    f32x4 accP[4][4] = {};
    for (int kt = 0; kt < 4; ++kt) {
        int k0 = kt * 64;
        __syncthreads();                         // kt=0: also publishes V1
        #pragma unroll
        for (int q = 0; q < 8; ++q) {            // 32 segs of W3t 256x64
            int seg = w * 8 + q;
            int rloc = seg * 8 + srow8;
            gl16(W3t + (size_t)rloc * 256 + k0 + sch * 8, &S2[17408 + seg * 512]);
        }
        __syncthreads();
        #pragma unroll
        for (int ss = 0; ss < 2; ++ss) {
            int cx = ((ss * 4 + (lane >> 4)) ^ fb7) * 8;
            s16x8 af[4], bf[4];
            #pragma unroll
            for (int i = 0; i < 4; ++i) {
                af[i] = *(const s16x8*)&V1[(i * 16 + fr) * 264 + k0 + ss * 32 + (lane >> 4) * 8];
                bf[i] = *(const s16x8*)&S2[17408 + (n0w + i * 16 + fr) * 64 + cx];
            }
            #pragma unroll
            for (int mi = 0; mi < 4; ++mi)
                #pragma unroll
                for (int ni = 0; ni < 4; ++ni)
                    accP[mi][ni] = __builtin_amdgcn_mfma_f32_16x16x32_bf16(af[mi], bf[ni], accP[mi][ni], 0, 0, 0);
        }
    }

    // out[j] = sum_d P[j][d] * V2[j][d]
    #pragma unroll
    for (int mi = 0; mi < 4; ++mi)
        #pragma unroll
        for (int reg = 0; reg < 4; ++reg) {
            float s = 0.f;
            #pragma unroll
            for (int ni = 0; ni < 4; ++ni) s += accP[mi][ni][reg] * v2[mi][ni][reg];
            s += __shfl_xor(s, 1); s += __shfl_xor(s, 2);
            s += __shfl_xor(s, 4); s += __shfl_xor(s, 8);
            if ((lane & 15) == 0)
                part[(mi * 16 + (lane >> 4) * 4 + reg) * 4 + w] = s;
        }
    __syncthreads();
    if (t < 64)
        out[(size_t)rg * 256 + j0 + t] = part[t*4] + part[t*4+1] + part[t*4+2] + part[t*4+3];
}

extern "C" void kernel_launch(void* const* d_in, const int* in_sizes, int n_in,
                              void* d_out, int out_size, void* d_ws, size_t ws_size,
                              hipStream_t stream) {
    const float* layer1 = (const float*)d_in[0];
    const float* layer2 = (const float*)d_in[1];
    const float* h1     = (const float*)d_in[2];
    const float* h2     = (const float*)d_in[3];
    const float* W1     = (const float*)d_in[4];
    const float* W2     = (const float*)d_in[5];
    const float* W3     = (const float*)d_in[6];
    float* out = (float*)d_out;

    short* Wp1  = (short*)d_ws;                  // 33.55 MB
    short* Wp2  = Wp1 + 16777216;
    short* l1b  = Wp2 + 16777216;                // 2048x256
    short* l2b  = l1b + 524288;
    short* W3t  = l2b + 524288;                  // 256x256
    short* Wtp1 = W3t + 65536;                   // 256x256
    short* Wtp2 = Wtp1 + 65536;
    float* tail1 = (float*)(Wtp2 + 65536);       // 2048x256 fp32
    float* tail2 = tail1 + 524288;
    short* T1   = (short*)(tail2 + 524288);
    const size_t head = (size_t)(16777216*2 + 524288*2 + 65536*3) * 2 + (size_t)524288 * 2 * 4;
    int chunk = 2048;
    while (head + (size_t)chunk * 262144 > ws_size && chunk > 128) chunk >>= 1;
    short* T2 = T1 + (size_t)chunk * 65536;

    conv_bf16<<<1024, 256, 0, stream>>>(layer1, layer2, l1b, l2b);
    prep_w3t<<<64, 256, 0, stream>>>(W3, W3t);
    prep_wtail<<<dim3(64, 2), 256, 0, stream>>>(W1, W2, Wtp1, Wtp2);
    prep_wp<<<dim3(64, 256, 2), 256, 0, stream>>>(W1, W2, Wp1, Wp2);
    tail_mfma<<<dim3(16, 2, 2), 256, 0, stream>>>(l1b, Wtp1, Wtp2, W1, W2, tail1, tail2);

    for (int row0 = 0; row0 < 2048; row0 += chunk) {
        stage1<<<dim3(chunk / 128, 2, 512), 256, 0, stream>>>(
            l1b, Wp1, Wp2, W1, W2, T1, T2, row0);
        stage2<<<dim3(4, chunk), 256, 0, stream>>>(
            l2b, T1, T2, tail1, tail2, h1, h2, W3t, out, row0);
    }
}